// Round 1
// baseline (1015.122 us; speedup 1.0000x reference)
//
#include <hip/hip_runtime.h>

#define LEAKC 0.1f

__device__ __forceinline__ float lrelu(float v){ return v > 0.f ? v : LEAKC*v; }

// ---------------- styles: style1=(2,32), style2=(2,64) ----------------
__global__ void style_kernel(const float* __restrict__ g,
                             const float* __restrict__ sp1,
                             const float* __restrict__ sp2,
                             float* __restrict__ s1, float* __restrict__ s2){
  int t = threadIdx.x;
  if (t < 64){
    int b = t >> 5, j = t & 31;
    float a = 0.f;
    for (int k=0;k<256;k++) a += g[b*256+k]*sp1[j*256+k];
    s1[t] = a;
  } else if (t < 192){
    int u = t - 64;
    int b = u >> 6, j = u & 63;
    float a = 0.f;
    for (int k=0;k<256;k++) a += g[b*256+k]*sp2[j*256+k];
    s2[u] = a;
  }
}

// ---------------- cls[b,t] = argmax_c label[t,b,c] ----------------
__global__ void cls_kernel(const float* __restrict__ label, int* __restrict__ cls){
  int n = threadIdx.x;              // 0..255, n = b*128 + t
  int b = n >> 7, t = n & 127;
  const float* p = label + (t*2 + b)*80;
  float best = p[0]; int bi = 0;
  for (int c=1;c<80;c++){ float v = p[c]; if (v > best){ best = v; bi = c; } }
  cls[n] = bi;
}

// ---------------- input conv 7x7, pad(0,3): x(2,1,64,512) -> (2,64,58,512), lrelu ----------------
__global__ void conv_in_kernel(const float* __restrict__ x,
                               const float* __restrict__ wgt,   // (64,1,7,7)
                               const float* __restrict__ bias,
                               float* __restrict__ out){
  int hw = blockIdx.x*256 + threadIdx.x;   // < 58*512 = 29696
  int y = hw >> 9, w = hw & 511;
  int b = blockIdx.z;
  int o0 = blockIdx.y * 8;
  float acc[8];
  #pragma unroll
  for (int i=0;i<8;i++) acc[i] = bias[o0+i];
  for (int kh=0;kh<7;kh++){
    const float* ip = x + (b*64 + y + kh)*512;
    #pragma unroll
    for (int kw=0;kw<7;kw++){
      int wi = w + kw - 3;
      float v = (wi>=0 && wi<512) ? ip[wi] : 0.f;
      #pragma unroll
      for (int i=0;i<8;i++) acc[i] += v * wgt[(o0+i)*49 + kh*7 + kw];
    }
  }
  #pragma unroll
  for (int i=0;i<8;i++)
    out[((b*64 + o0+i)*58 + y)*512 + w] = lrelu(acc[i]);
}

// ---------------- generic 3x3 conv, pad(0,1), with virtual concat channels ----------------
// channel order: [0,CM) from `in` (B,CM,HIN,WID); [CM,CM+CS) broadcast style (B,CS);
// [.. +CSP) spaced_style (128,2,32) indexed by column; [.. +CLAB) label (128,2,80) by column.
template<int CM, int CS, int CSP, int CLAB, int HIN, int WID, int COUT, bool LEAKY>
__global__ void conv3_kernel(const float* __restrict__ in,
                             const float* __restrict__ style,
                             const float* __restrict__ sstyle,
                             const float* __restrict__ lab,
                             const float* __restrict__ wgt,    // (COUT, CT, 3, 3)
                             const float* __restrict__ bias,
                             float* __restrict__ out){
  constexpr int CT = CM + CS + CSP + CLAB;
  constexpr int HOUT = HIN - 2;
  int hw = blockIdx.x*256 + threadIdx.x;
  if (hw >= HOUT*WID) return;
  int y = hw / WID, w = hw % WID;
  int b = blockIdx.z;
  int o0 = blockIdx.y * 8;
  float acc[8];
  #pragma unroll
  for (int i=0;i<8;i++) acc[i] = bias[o0+i];

  const bool lok = (w > 0), rok = (w < WID-1);

  for (int c=0;c<CM;c++){
    const float* ip = in + ((b*CM + c)*HIN + y)*WID + w;
    const float* wp = wgt + (o0*CT + c)*9;
    #pragma unroll
    for (int kh=0;kh<3;kh++){
      float v0 = lok ? ip[kh*WID - 1] : 0.f;
      float v1 = ip[kh*WID];
      float v2 = rok ? ip[kh*WID + 1] : 0.f;
      #pragma unroll
      for (int i=0;i<8;i++){
        const float* wq = wp + i*CT*9 + kh*3;
        acc[i] += v0*wq[0] + v1*wq[1] + v2*wq[2];
      }
    }
  }
  if (CS > 0){
    for (int c=0;c<CS;c++){
      float sval = style[b*CS + c];
      const float* wp = wgt + (o0*CT + CM + c)*9;
      float v0 = lok ? sval : 0.f;
      float v2 = rok ? sval : 0.f;
      #pragma unroll
      for (int i=0;i<8;i++){
        const float* wq = wp + i*CT*9;
        acc[i] += v0*(wq[0]+wq[3]+wq[6]) + sval*(wq[1]+wq[4]+wq[7]) + v2*(wq[2]+wq[5]+wq[8]);
      }
    }
  }
  if (CSP > 0){
    for (int c=0;c<CSP;c++){
      const float* wp = wgt + (o0*CT + CM + CS + c)*9;
      float v0 = lok ? sstyle[((w-1)*2 + b)*32 + c] : 0.f;
      float v1 = sstyle[(w*2 + b)*32 + c];
      float v2 = rok ? sstyle[((w+1)*2 + b)*32 + c] : 0.f;
      #pragma unroll
      for (int i=0;i<8;i++){
        const float* wq = wp + i*CT*9;
        acc[i] += v0*(wq[0]+wq[3]+wq[6]) + v1*(wq[1]+wq[4]+wq[7]) + v2*(wq[2]+wq[5]+wq[8]);
      }
    }
  }
  if (CLAB > 0){
    for (int c=0;c<CLAB;c++){
      const float* wp = wgt + (o0*CT + CM + CS + CSP + c)*9;
      float v0 = lok ? lab[((w-1)*2 + b)*80 + c] : 0.f;
      float v1 = lab[(w*2 + b)*80 + c];
      float v2 = rok ? lab[((w+1)*2 + b)*80 + c] : 0.f;
      #pragma unroll
      for (int i=0;i<8;i++){
        const float* wq = wp + i*CT*9;
        acc[i] += v0*(wq[0]+wq[3]+wq[6]) + v1*(wq[1]+wq[4]+wq[7]) + v2*(wq[2]+wq[5]+wq[8]);
      }
    }
  }
  #pragma unroll
  for (int i=0;i<8;i++){
    float v = acc[i];
    if (LEAKY) v = lrelu(v);
    out[((b*COUT + o0+i)*HOUT + y)*WID + w] = v;
  }
}

// ---------------- 2x2 mean pool ----------------
__global__ void pool2_kernel(const float* __restrict__ in, float* __restrict__ out,
                             int H, int W, int total){
  int n = blockIdx.x*256 + threadIdx.x;
  if (n >= total) return;
  int Wo = W >> 1;
  int wo = n % Wo;
  int r = n / Wo;
  int Ho = H >> 1;
  int ho = r % Ho;
  int bc = r / Ho;
  const float* p = in + (bc*H + 2*ho)*W + 2*wo;
  out[n] = 0.25f*(p[0] + p[1] + p[W] + p[W+1]);
}

// ---------------- pM = conv3(A7, fm_w) + fm_b : (2,256,3,64) -> (2,1,1,64) ----------------
__global__ void fm_kernel(const float* __restrict__ A7,
                          const float* __restrict__ fw,   // (1,256,3,3)
                          const float* __restrict__ fb,
                          float* __restrict__ out){
  int n = threadIdx.x;   // 0..127
  int b = n >> 6, w = n & 63;
  float a = fb[0];
  for (int c=0;c<256;c++){
    #pragma unroll
    for (int kh=0;kh<3;kh++){
      const float* ip = A7 + ((b*256+c)*3+kh)*64;
      const float* wp = fw + (c*3+kh)*3;
      #pragma unroll
      for (int kw=0;kw<3;kw++){
        int wi = w + kw - 1;
        if (wi>=0 && wi<64) a += ip[wi]*wp[kw];
      }
    }
  }
  out[n] = a;
}

// ---------------- char discriminator: one block per n=(b,t) ----------------
__global__ __launch_bounds__(128) void cd_kernel(
    const float* __restrict__ A7,     // (2,256,3,64)
    const int*   __restrict__ clsb,   // (256)
    const float* __restrict__ Wc,     // (80,128,2304)
    const float* __restrict__ bc,     // (80,128)
    const float* __restrict__ cstyle, // (2,80,32)
    const float* __restrict__ W1,     // (80,160,128)
    const float* __restrict__ b1,     // (80,128)
    const float* __restrict__ W2,     // (80,128,1)
    const float* __restrict__ b2,     // (80,1)
    float* __restrict__ pChar)        // (256)
{
  __shared__ float patch[256*15];     // [c][r][j], j = padded col idx-2..idx+2
  __shared__ float feat[160];
  __shared__ float red2[2];
  int n = blockIdx.x, tid = threadIdx.x;
  int b = n >> 7, t = n & 127;
  int e = clsb[n];
  int idx = t >> 1;

  for (int i=tid; i<3840; i+=128){
    int c = i/15, rj = i%15, r = rj/5, j = rj%5;
    int wc = idx - 2 + j;
    patch[i] = (wc >= 0 && wc < 64) ? A7[((b*256+c)*3+r)*64 + wc] : 0.f;
  }
  __syncthreads();

  int o = tid;  // 0..127
  float a0=0.f, a1=0.f, a2=0.f;
  const float* wp = Wc + (e*128 + o)*2304;
  for (int c=0;c<256;c++){
    #pragma unroll
    for (int r=0;r<3;r++){
      const float* pp = patch + (c*3+r)*5;
      const float* wq = wp + (c*3+r)*3;
      float w0=wq[0], w1=wq[1], w2=wq[2];
      float p0=pp[0], p1=pp[1], p2=pp[2], p3=pp[3], p4=pp[4];
      a0 += p0*w0 + p1*w1 + p2*w2;
      a1 += p1*w0 + p2*w1 + p3*w2;
      a2 += p2*w0 + p3*w1 + p4*w2;
    }
  }
  float bb = bc[e*128 + o];
  a0 += bb; a1 += bb; a2 += bb;
  float pooled = (lrelu(a0)+lrelu(a1)+lrelu(a2)) * (1.f/3.f);
  feat[o] = pooled;
  if (tid < 32) feat[128+tid] = cstyle[(b*80 + e)*32 + tid];
  __syncthreads();

  float s = b1[e*128 + o];
  for (int d=0;d<160;d++) s += feat[d]*W1[(e*160 + d)*128 + o];
  float h = s > 0.f ? s : 0.f;
  float contrib = h * W2[e*128 + o];
  #pragma unroll
  for (int off=32; off>0; off>>=1) contrib += __shfl_down(contrib, off, 64);
  if ((tid & 63) == 0) red2[tid>>6] = contrib;
  __syncthreads();
  if (tid == 0) pChar[n] = red2[0] + red2[1] + b2[e];
}

extern "C" void kernel_launch(void* const* d_in, const int* in_sizes, int n_in,
                              void* d_out, int out_size, void* d_ws, size_t ws_size,
                              hipStream_t stream){
  (void)in_sizes; (void)n_in; (void)out_size; (void)ws_size;
  const float* x      = (const float*)d_in[0];
  const float* label  = (const float*)d_in[1];
  const float* g_style= (const float*)d_in[2];
  const float* spaced = (const float*)d_in[3];
  const float* cstyle = (const float*)d_in[4];
  const float* sp1    = (const float*)d_in[5];
  const float* sp2    = (const float*)d_in[6];
  const float* in_w   = (const float*)d_in[7];
  const float* in_b   = (const float*)d_in[8];
  const float* c1w1   = (const float*)d_in[9];
  const float* c1b1   = (const float*)d_in[10];
  const float* c1w2   = (const float*)d_in[11];
  const float* c1b2   = (const float*)d_in[12];
  const float* c2w    = (const float*)d_in[13];
  const float* c2b    = (const float*)d_in[14];
  const float* c3w1   = (const float*)d_in[15];
  const float* c3b1   = (const float*)d_in[16];
  const float* c3w2   = (const float*)d_in[17];
  const float* c3b2   = (const float*)d_in[18];
  const float* fm_w   = (const float*)d_in[19];
  const float* fm_b   = (const float*)d_in[20];
  const float* cdw    = (const float*)d_in[21];
  const float* cdb    = (const float*)d_in[22];
  const float* fc1w   = (const float*)d_in[23];
  const float* fc1b   = (const float*)d_in[24];
  const float* fc2w   = (const float*)d_in[25];
  const float* fc2b   = (const float*)d_in[26];
  float* out = (float*)d_out;

  char* ws = (char*)d_ws;
  float* buf0 = (float*)ws;                   // up to 15.3 MB
  float* buf1 = (float*)(ws + (16u<<20));     // up to 14.7 MB
  float* s1   = (float*)(ws + (31u<<20));
  float* s2   = s1 + 64;
  int*   clsb = (int*)(s2 + 128);

  style_kernel<<<1,256,0,stream>>>(g_style, sp1, sp2, s1, s2);
  cls_kernel<<<1,256,0,stream>>>(label, clsb);

  // h1 (2,64,58,512) -> buf0
  conv_in_kernel<<<dim3(116,8,2),256,0,stream>>>(x, in_w, in_b, buf0);
  // A2 (2,64,56,512) -> buf1   (concat h1 + style1)
  conv3_kernel<64,32,0,0,58,512,64,true><<<dim3(112,8,2),256,0,stream>>>(buf0, s1, nullptr, nullptr, c1w1, c1b1, buf1);
  // P3 (2,64,28,256) -> buf0
  pool2_kernel<<<3584,256,0,stream>>>(buf1, buf0, 56, 512, 917504);
  // A4 (2,128,26,256) -> buf1
  conv3_kernel<64,0,0,0,28,256,128,true><<<dim3(26,16,2),256,0,stream>>>(buf0, nullptr,nullptr,nullptr, c1w2, c1b2, buf1);
  // A5 (2,128,24,256) -> buf0  (concat A4 + style2)
  conv3_kernel<128,64,0,0,26,256,128,true><<<dim3(24,16,2),256,0,stream>>>(buf1, s2, nullptr,nullptr, c2w, c2b, buf0);
  // P5 (2,128,12,128) -> buf1
  pool2_kernel<<<1536,256,0,stream>>>(buf0, buf1, 24, 256, 393216);
  // A6 (2,128,10,128) -> buf0  (concat P5 + spaced_style + label)
  conv3_kernel<128,0,32,80,12,128,128,true><<<dim3(5,16,2),256,0,stream>>>(buf1, nullptr, spaced, label, c3w1, c3b1, buf0);
  // P6 (2,128,5,64) -> buf1
  pool2_kernel<<<320,256,0,stream>>>(buf0, buf1, 10, 128, 81920);
  // A7 (2,256,3,64) -> buf0
  conv3_kernel<128,0,0,0,5,64,256,true><<<dim3(1,32,2),256,0,stream>>>(buf1, nullptr,nullptr,nullptr, c3w2, c3b2, buf0);
  // pM -> out[0..128)
  fm_kernel<<<1,128,0,stream>>>(buf0, fm_w, fm_b, out);
  // pChar -> out[128..384)
  cd_kernel<<<256,128,0,stream>>>(buf0, clsb, cdw, cdb, cstyle, fc1w, fc1b, fc2w, fc2b, out + 128);
}

// Round 2
// 671.543 us; speedup vs baseline: 1.5116x; 1.5116x over previous
//
#include <hip/hip_runtime.h>

#define LEAKC 0.1f

__device__ __forceinline__ float lrelu(float v){ return v > 0.f ? v : LEAKC*v; }

// ---------------- styles: style1=(2,32), style2=(2,64) ----------------
__global__ void style_kernel(const float* __restrict__ g,
                             const float* __restrict__ sp1,
                             const float* __restrict__ sp2,
                             float* __restrict__ s1, float* __restrict__ s2){
  int t = threadIdx.x;
  if (t < 64){
    int b = t >> 5, j = t & 31;
    float a = 0.f;
    for (int k=0;k<256;k++) a += g[b*256+k]*sp1[j*256+k];
    s1[t] = a;
  } else if (t < 192){
    int u = t - 64;
    int b = u >> 6, j = u & 63;
    float a = 0.f;
    for (int k=0;k<256;k++) a += g[b*256+k]*sp2[j*256+k];
    s2[u] = a;
  }
}

// ---------------- cls[b,t] = argmax_c label[t,b,c] ----------------
__global__ void cls_kernel(const float* __restrict__ label, int* __restrict__ cls){
  int n = threadIdx.x;              // 0..255, n = b*128 + t
  int b = n >> 7, t = n & 127;
  const float* p = label + (t*2 + b)*80;
  float best = p[0]; int bi = 0;
  for (int c=1;c<80;c++){ float v = p[c]; if (v > best){ best = v; bi = c; } }
  cls[n] = bi;
}

// ---------------- input conv 7x7, pad(0,3): x(2,1,64,512) -> (2,64,58,512), lrelu ----------------
__global__ void conv_in_kernel(const float* __restrict__ x,
                               const float* __restrict__ wgt,   // (64,1,7,7)
                               const float* __restrict__ bias,
                               float* __restrict__ out){
  int hw = blockIdx.x*256 + threadIdx.x;   // < 58*512 = 29696
  int y = hw >> 9, w = hw & 511;
  int b = blockIdx.z;
  int o0 = blockIdx.y * 8;
  float acc[8];
  #pragma unroll
  for (int i=0;i<8;i++) acc[i] = bias[o0+i];
  for (int kh=0;kh<7;kh++){
    const float* ip = x + (b*64 + y + kh)*512;
    #pragma unroll
    for (int kw=0;kw<7;kw++){
      int wi = w + kw - 3;
      float v = (wi>=0 && wi<512) ? ip[wi] : 0.f;
      #pragma unroll
      for (int i=0;i<8;i++) acc[i] += v * wgt[(o0+i)*49 + kh*7 + kw];
    }
  }
  #pragma unroll
  for (int i=0;i<8;i++)
    out[((b*64 + o0+i)*58 + y)*512 + w] = lrelu(acc[i]);
}

// ---------------- generic 3x3 conv, pad(0,1), with virtual concat channels ----------------
// channel order: [0,CM) from `in` (B,CM,HIN,WID); [CM,CM+CS) broadcast style (B,CS);
// [.. +CSP) spaced_style (128,2,32) indexed by column; [.. +CLAB) label (128,2,80) by column.
// OPT = output channels per thread; blockIdx.y covers COUT/OPT.
template<int CM, int CS, int CSP, int CLAB, int HIN, int WID, int COUT, int OPT, bool LEAKY>
__global__ void conv3_kernel(const float* __restrict__ in,
                             const float* __restrict__ style,
                             const float* __restrict__ sstyle,
                             const float* __restrict__ lab,
                             const float* __restrict__ wgt,    // (COUT, CT, 3, 3)
                             const float* __restrict__ bias,
                             float* __restrict__ out){
  constexpr int CT = CM + CS + CSP + CLAB;
  constexpr int HOUT = HIN - 2;
  int hw = blockIdx.x*256 + threadIdx.x;
  if (hw >= HOUT*WID) return;
  int y = hw / WID, w = hw % WID;
  int b = blockIdx.z;
  int o0 = blockIdx.y * OPT;
  float acc[OPT];
  #pragma unroll
  for (int i=0;i<OPT;i++) acc[i] = bias[o0+i];

  const bool lok = (w > 0), rok = (w < WID-1);

  for (int c=0;c<CM;c++){
    const float* ip = in + ((b*CM + c)*HIN + y)*WID + w;
    const float* wp = wgt + (o0*CT + c)*9;
    #pragma unroll
    for (int kh=0;kh<3;kh++){
      float v0 = lok ? ip[kh*WID - 1] : 0.f;
      float v1 = ip[kh*WID];
      float v2 = rok ? ip[kh*WID + 1] : 0.f;
      #pragma unroll
      for (int i=0;i<OPT;i++){
        const float* wq = wp + i*CT*9 + kh*3;
        acc[i] += v0*wq[0] + v1*wq[1] + v2*wq[2];
      }
    }
  }
  if (CS > 0){
    for (int c=0;c<CS;c++){
      float sval = style[b*CS + c];
      const float* wp = wgt + (o0*CT + CM + c)*9;
      float v0 = lok ? sval : 0.f;
      float v2 = rok ? sval : 0.f;
      #pragma unroll
      for (int i=0;i<OPT;i++){
        const float* wq = wp + i*CT*9;
        acc[i] += v0*(wq[0]+wq[3]+wq[6]) + sval*(wq[1]+wq[4]+wq[7]) + v2*(wq[2]+wq[5]+wq[8]);
      }
    }
  }
  if (CSP > 0){
    for (int c=0;c<CSP;c++){
      const float* wp = wgt + (o0*CT + CM + CS + c)*9;
      float v0 = lok ? sstyle[((w-1)*2 + b)*32 + c] : 0.f;
      float v1 = sstyle[(w*2 + b)*32 + c];
      float v2 = rok ? sstyle[((w+1)*2 + b)*32 + c] : 0.f;
      #pragma unroll
      for (int i=0;i<OPT;i++){
        const float* wq = wp + i*CT*9;
        acc[i] += v0*(wq[0]+wq[3]+wq[6]) + v1*(wq[1]+wq[4]+wq[7]) + v2*(wq[2]+wq[5]+wq[8]);
      }
    }
  }
  if (CLAB > 0){
    for (int c=0;c<CLAB;c++){
      const float* wp = wgt + (o0*CT + CM + CS + CSP + c)*9;
      float v0 = lok ? lab[((w-1)*2 + b)*80 + c] : 0.f;
      float v1 = lab[(w*2 + b)*80 + c];
      float v2 = rok ? lab[((w+1)*2 + b)*80 + c] : 0.f;
      #pragma unroll
      for (int i=0;i<OPT;i++){
        const float* wq = wp + i*CT*9;
        acc[i] += v0*(wq[0]+wq[3]+wq[6]) + v1*(wq[1]+wq[4]+wq[7]) + v2*(wq[2]+wq[5]+wq[8]);
      }
    }
  }
  #pragma unroll
  for (int i=0;i<OPT;i++){
    float v = acc[i];
    if (LEAKY) v = lrelu(v);
    out[((b*COUT + o0+i)*HOUT + y)*WID + w] = v;
  }
}

// ---------------- 2x2 mean pool ----------------
__global__ void pool2_kernel(const float* __restrict__ in, float* __restrict__ out,
                             int H, int W, int total){
  int n = blockIdx.x*256 + threadIdx.x;
  if (n >= total) return;
  int Wo = W >> 1;
  int wo = n % Wo;
  int r = n / Wo;
  int Ho = H >> 1;
  int ho = r % Ho;
  int bc = r / Ho;
  const float* p = in + (bc*H + 2*ho)*W + 2*wo;
  out[n] = 0.25f*(p[0] + p[1] + p[W] + p[W+1]);
}

// ---------------- pM: one block per output (b,w); 256 threads = input channels ----------------
__global__ __launch_bounds__(256) void fm_kernel(const float* __restrict__ A7,
                          const float* __restrict__ fw,   // (1,256,3,3)
                          const float* __restrict__ fb,
                          float* __restrict__ out){
  __shared__ float red[4];
  int n = blockIdx.x;      // 0..127
  int b = n >> 6, w = n & 63;
  int c = threadIdx.x;     // 0..255
  float a = 0.f;
  #pragma unroll
  for (int r=0;r<3;r++){
    const float* ip = A7 + ((b*256+c)*3+r)*64;
    const float* wp = fw + (c*3+r)*3;
    #pragma unroll
    for (int kw=0;kw<3;kw++){
      int wi = w + kw - 1;
      if (wi>=0 && wi<64) a += ip[wi]*wp[kw];
    }
  }
  #pragma unroll
  for (int off=32; off>0; off>>=1) a += __shfl_down(a, off, 64);
  if ((threadIdx.x & 63) == 0) red[threadIdx.x>>6] = a;
  __syncthreads();
  if (threadIdx.x == 0) out[n] = red[0]+red[1]+red[2]+red[3] + fb[0];
}

// ---------------- char discriminator: one block per n=(b,t), 256 threads ----------------
// threads split: o = tid&127 (output channel), half = tid>>7 (input-channel half)
__global__ __launch_bounds__(256) void cd_kernel(
    const float* __restrict__ A7,     // (2,256,3,64)
    const int*   __restrict__ clsb,   // (256)
    const float* __restrict__ Wc,     // (80,128,2304)
    const float* __restrict__ bc,     // (80,128)
    const float* __restrict__ cstyle, // (2,80,32)
    const float* __restrict__ W1,     // (80,160,128)
    const float* __restrict__ b1,     // (80,128)
    const float* __restrict__ W2,     // (80,128,1)
    const float* __restrict__ b2,     // (80,1)
    float* __restrict__ pChar)        // (256)
{
  __shared__ float patch[256*15];     // [c][r][j], j = padded col idx-2..idx+2
  __shared__ float part[128*3];
  __shared__ float feat[160];
  __shared__ float red2[2];
  int n = blockIdx.x, tid = threadIdx.x;
  int b = n >> 7, t = n & 127;
  int e = clsb[n];
  int idx = t >> 1;

  for (int i=tid; i<3840; i+=256){
    int c = i/15, rj = i%15, r = rj/5, j = rj%5;
    int wc = idx - 2 + j;
    patch[i] = (wc >= 0 && wc < 64) ? A7[((b*256+c)*3+r)*64 + wc] : 0.f;
  }
  __syncthreads();

  int o = tid & 127, half = tid >> 7;
  float a0=0.f, a1=0.f, a2=0.f;
  const float* wp = Wc + (e*128 + o)*2304 + half*128*9;
  const float* pbase = patch + half*128*15;
  for (int c=0;c<128;c++){
    #pragma unroll
    for (int r=0;r<3;r++){
      const float* pp = pbase + c*15 + r*5;
      const float* wq = wp + (c*3+r)*3;
      float w0=wq[0], w1=wq[1], w2=wq[2];
      float p0=pp[0], p1=pp[1], p2=pp[2], p3=pp[3], p4=pp[4];
      a0 += p0*w0 + p1*w1 + p2*w2;
      a1 += p1*w0 + p2*w1 + p3*w2;
      a2 += p2*w0 + p3*w1 + p4*w2;
    }
  }
  if (half == 1){ part[o*3] = a0; part[o*3+1] = a1; part[o*3+2] = a2; }
  __syncthreads();
  if (half == 0){
    a0 += part[o*3]; a1 += part[o*3+1]; a2 += part[o*3+2];
    float bb = bc[e*128 + o];
    a0 += bb; a1 += bb; a2 += bb;
    float pooled = (lrelu(a0)+lrelu(a1)+lrelu(a2)) * (1.f/3.f);
    feat[o] = pooled;
  }
  if (tid >= 128 && tid < 160) feat[128 + (tid-128)] = cstyle[(b*80 + e)*32 + (tid-128)];
  __syncthreads();

  float contrib = 0.f;
  if (half == 0){
    float s = b1[e*128 + o];
    for (int d=0;d<160;d++) s += feat[d]*W1[(e*160 + d)*128 + o];
    float h = s > 0.f ? s : 0.f;
    contrib = h * W2[e*128 + o];
    #pragma unroll
    for (int off=32; off>0; off>>=1) contrib += __shfl_down(contrib, off, 64);
    if ((tid & 63) == 0) red2[tid>>6] = contrib;
  }
  __syncthreads();
  if (tid == 0) pChar[n] = red2[0] + red2[1] + b2[e];
}

extern "C" void kernel_launch(void* const* d_in, const int* in_sizes, int n_in,
                              void* d_out, int out_size, void* d_ws, size_t ws_size,
                              hipStream_t stream){
  (void)in_sizes; (void)n_in; (void)out_size; (void)ws_size;
  const float* x      = (const float*)d_in[0];
  const float* label  = (const float*)d_in[1];
  const float* g_style= (const float*)d_in[2];
  const float* spaced = (const float*)d_in[3];
  const float* cstyle = (const float*)d_in[4];
  const float* sp1    = (const float*)d_in[5];
  const float* sp2    = (const float*)d_in[6];
  const float* in_w   = (const float*)d_in[7];
  const float* in_b   = (const float*)d_in[8];
  const float* c1w1   = (const float*)d_in[9];
  const float* c1b1   = (const float*)d_in[10];
  const float* c1w2   = (const float*)d_in[11];
  const float* c1b2   = (const float*)d_in[12];
  const float* c2w    = (const float*)d_in[13];
  const float* c2b    = (const float*)d_in[14];
  const float* c3w1   = (const float*)d_in[15];
  const float* c3b1   = (const float*)d_in[16];
  const float* c3w2   = (const float*)d_in[17];
  const float* c3b2   = (const float*)d_in[18];
  const float* fm_w   = (const float*)d_in[19];
  const float* fm_b   = (const float*)d_in[20];
  const float* cdw    = (const float*)d_in[21];
  const float* cdb    = (const float*)d_in[22];
  const float* fc1w   = (const float*)d_in[23];
  const float* fc1b   = (const float*)d_in[24];
  const float* fc2w   = (const float*)d_in[25];
  const float* fc2b   = (const float*)d_in[26];
  float* out = (float*)d_out;

  char* ws = (char*)d_ws;
  float* buf0 = (float*)ws;                   // up to 15.3 MB
  float* buf1 = (float*)(ws + (16u<<20));     // up to 14.7 MB
  float* s1   = (float*)(ws + (31u<<20));
  float* s2   = s1 + 64;
  int*   clsb = (int*)(s2 + 128);

  style_kernel<<<1,256,0,stream>>>(g_style, sp1, sp2, s1, s2);
  cls_kernel<<<1,256,0,stream>>>(label, clsb);

  // h1 (2,64,58,512) -> buf0
  conv_in_kernel<<<dim3(116,8,2),256,0,stream>>>(x, in_w, in_b, buf0);
  // A2 (2,64,56,512) -> buf1   (concat h1 + style1)
  conv3_kernel<64,32,0,0,58,512,64,8,true><<<dim3(112,8,2),256,0,stream>>>(buf0, s1, nullptr, nullptr, c1w1, c1b1, buf1);
  // P3 (2,64,28,256) -> buf0
  pool2_kernel<<<3584,256,0,stream>>>(buf1, buf0, 56, 512, 917504);
  // A4 (2,128,26,256) -> buf1
  conv3_kernel<64,0,0,0,28,256,128,8,true><<<dim3(26,16,2),256,0,stream>>>(buf0, nullptr,nullptr,nullptr, c1w2, c1b2, buf1);
  // A5 (2,128,24,256) -> buf0  (concat A4 + style2)
  conv3_kernel<128,64,0,0,26,256,128,8,true><<<dim3(24,16,2),256,0,stream>>>(buf1, s2, nullptr,nullptr, c2w, c2b, buf0);
  // P5 (2,128,12,128) -> buf1
  pool2_kernel<<<1536,256,0,stream>>>(buf0, buf1, 24, 256, 393216);
  // A6 (2,128,10,128) -> buf0  (concat P5 + spaced_style + label)  OPT=4 -> 320 blocks
  conv3_kernel<128,0,32,80,12,128,128,4,true><<<dim3(5,32,2),256,0,stream>>>(buf1, nullptr, spaced, label, c3w1, c3b1, buf0);
  // P6 (2,128,5,64) -> buf1
  pool2_kernel<<<320,256,0,stream>>>(buf0, buf1, 10, 128, 81920);
  // A7 (2,256,3,64) -> buf0   OPT=2 -> 256 blocks
  conv3_kernel<128,0,0,0,5,64,256,2,true><<<dim3(1,128,2),256,0,stream>>>(buf1, nullptr,nullptr,nullptr, c3w2, c3b2, buf0);
  // pM -> out[0..128)
  fm_kernel<<<128,256,0,stream>>>(buf0, fm_w, fm_b, out);
  // pChar -> out[128..384)
  cd_kernel<<<256,256,0,stream>>>(buf0, clsb, cdw, cdb, cstyle, fc1w, fc1b, fc2w, fc2b, out + 128);
}

// Round 3
// 412.863 us; speedup vs baseline: 2.4587x; 1.6266x over previous
//
#include <hip/hip_runtime.h>

#define LEAKC 0.1f

__device__ __forceinline__ float lrelu(float v){ return v > 0.f ? v : LEAKC*v; }

// ---------------- styles: style1=(2,32), style2=(2,64) ----------------
__global__ void style_kernel(const float* __restrict__ g,
                             const float* __restrict__ sp1,
                             const float* __restrict__ sp2,
                             float* __restrict__ s1, float* __restrict__ s2){
  int t = threadIdx.x;
  if (t < 64){
    int b = t >> 5, j = t & 31;
    float a = 0.f;
    for (int k=0;k<256;k++) a += g[b*256+k]*sp1[j*256+k];
    s1[t] = a;
  } else if (t < 192){
    int u = t - 64;
    int b = u >> 6, j = u & 63;
    float a = 0.f;
    for (int k=0;k<256;k++) a += g[b*256+k]*sp2[j*256+k];
    s2[u] = a;
  }
}

// ---------------- cls[b,t] = argmax_c label[t,b,c] ----------------
__global__ void cls_kernel(const float* __restrict__ label, int* __restrict__ cls){
  int n = threadIdx.x;              // 0..255, n = b*128 + t
  int b = n >> 7, t = n & 127;
  const float* p = label + (t*2 + b)*80;
  float best = p[0]; int bi = 0;
  for (int c=1;c<80;c++){ float v = p[c]; if (v > best){ best = v; bi = c; } }
  cls[n] = bi;
}

// ---------------- input conv 7x7, pad(0,3): x(2,1,64,512) -> (2,64,58,512), lrelu ----------------
__global__ void conv_in_kernel(const float* __restrict__ x,
                               const float* __restrict__ wgt,   // (64,1,7,7)
                               const float* __restrict__ bias,
                               float* __restrict__ out){
  int hw = blockIdx.x*256 + threadIdx.x;   // < 58*512 = 29696
  int y = hw >> 9, w = hw & 511;
  int b = blockIdx.z;
  int o0 = blockIdx.y * 8;
  float acc[8];
  #pragma unroll
  for (int i=0;i<8;i++) acc[i] = bias[o0+i];
  for (int kh=0;kh<7;kh++){
    const float* ip = x + (b*64 + y + kh)*512;
    #pragma unroll
    for (int kw=0;kw<7;kw++){
      int wi = w + kw - 3;
      float v = (wi>=0 && wi<512) ? ip[wi] : 0.f;
      #pragma unroll
      for (int i=0;i<8;i++) acc[i] += v * wgt[(o0+i)*49 + kh*7 + kw];
    }
  }
  #pragma unroll
  for (int i=0;i<8;i++)
    out[((b*64 + o0+i)*58 + y)*512 + w] = lrelu(acc[i]);
}

// ---------------- main 3x3 conv over CM real channels, K-split partials ----------------
// part layout: [split][b][o][y][w]; grid: x = spatial/(256*PW), y = (COUT/OPT)*SPLIT, z = B
template<int CM,int CTOT,int HIN,int WID,int COUT,int OPT,int PW,int SPLIT>
__global__ void conv3_main(const float* __restrict__ in,
                           const float* __restrict__ wgt,   // (COUT, CTOT, 3, 3)
                           float* __restrict__ part){
  constexpr int HOUT = HIN - 2;
  constexpr int CSPLIT = CM / SPLIT;
  constexpr int N = 2*COUT*HOUT*WID;
  int hw0 = blockIdx.x*(256*PW) + threadIdx.x*PW;
  if (hw0 >= HOUT*WID) return;
  int y = hw0 / WID, w0 = hw0 % WID;
  int b = blockIdx.z;
  int yy = blockIdx.y;
  int split = yy % SPLIT;
  int o0 = (yy / SPLIT) * OPT;

  float acc[OPT][PW];
  #pragma unroll
  for (int i=0;i<OPT;i++)
    #pragma unroll
    for (int p=0;p<PW;p++) acc[i][p] = 0.f;

  const bool lok = (w0 > 0), rok = (w0 + PW) < WID;
  int c0 = split * CSPLIT;
  for (int c=c0; c<c0+CSPLIT; c++){
    const float* rp = in + ((b*CM + c)*HIN + y)*WID + w0;
    #pragma unroll
    for (int kh=0;kh<3;kh++){
      float v[PW+2];
      v[0] = lok ? rp[kh*WID - 1] : 0.f;
      #pragma unroll
      for (int j=0;j<PW;j++) v[1+j] = rp[kh*WID + j];
      v[PW+1] = rok ? rp[kh*WID + PW] : 0.f;
      #pragma unroll
      for (int i=0;i<OPT;i++){
        const float* wq = wgt + ((size_t)(o0+i)*CTOT + c)*9 + kh*3;
        float w0c=wq[0], w1c=wq[1], w2c=wq[2];
        #pragma unroll
        for (int p=0;p<PW;p++)
          acc[i][p] += v[p]*w0c + v[p+1]*w1c + v[p+2]*w2c;
      }
    }
  }
  #pragma unroll
  for (int i=0;i<OPT;i++){
    int base = split*N + ((b*COUT + o0+i)*HOUT + y)*WID + w0;
    #pragma unroll
    for (int p=0;p<PW;p++) part[base+p] = acc[i][p];
  }
}

// ---------------- combine partials + additive map + lrelu, float4, in-place over split 0 ----------------
// MODE 0: +bias[o]; MODE 1: 3-value map per (b,o) {left,interior,right}; MODE 2: full (b,o,w) map
template<int SPLIT,int MODE,int COUT,int HOUT,int WID>
__global__ __launch_bounds__(256) void combine_kernel(float* __restrict__ part,
                                                      const float* __restrict__ mapv,
                                                      const float* __restrict__ bias){
  constexpr int N = 2*COUT*HOUT*WID;
  int idx = (blockIdx.x*256 + threadIdx.x)*4;
  if (idx >= N) return;
  float4 v = *(float4*)(part + idx);
  #pragma unroll
  for (int s=1;s<SPLIT;s++){
    float4 u = *(const float4*)(part + (size_t)s*N + idx);
    v.x += u.x; v.y += u.y; v.z += u.z; v.w += u.w;
  }
  int w = idx % WID;
  int r = idx / WID;
  int bo = r / HOUT;
  int o = bo % COUT, b = bo / COUT;
  float* av = (float*)&v;
  if (MODE == 0){
    float bb = bias[o];
    #pragma unroll
    for (int j=0;j<4;j++) av[j] += bb;
  } else if (MODE == 1){
    const float* m = mapv + (size_t)(b*COUT + o)*3;
    #pragma unroll
    for (int j=0;j<4;j++){
      int wj = w + j;
      av[j] += (wj == 0) ? m[0] : ((wj == WID-1) ? m[2] : m[1]);
    }
  } else {
    const float* m = mapv + ((size_t)(b*COUT + o))*WID + w;
    #pragma unroll
    for (int j=0;j<4;j++) av[j] += m[j];
  }
  #pragma unroll
  for (int j=0;j<4;j++) av[j] = lrelu(av[j]);
  *(float4*)(part + idx) = v;
}

// ---------------- 3-value style map (broadcast style channels) ----------------
template<int CS,int CTOT,int COUT,int COFF>
__global__ void map3_kernel(const float* __restrict__ style,  // (2,CS)
                            const float* __restrict__ wgt,    // (COUT,CTOT,3,3)
                            const float* __restrict__ bias,
                            float* __restrict__ mapv){        // (2,COUT,3)
  int t = threadIdx.x;
  if (t >= 2*COUT) return;
  int b = t / COUT, o = t % COUT;
  float S0=0.f, S1=0.f, S2=0.f;
  for (int c=0;c<CS;c++){
    float s = style[b*CS + c];
    const float* wq = wgt + ((size_t)o*CTOT + COFF + c)*9;
    S0 += s*(wq[0]+wq[3]+wq[6]);
    S1 += s*(wq[1]+wq[4]+wq[7]);
    S2 += s*(wq[2]+wq[5]+wq[8]);
  }
  float bb = bias[o];
  mapv[t*3+0] = S1+S2+bb;      // w == 0
  mapv[t*3+1] = S0+S1+S2+bb;   // interior
  mapv[t*3+2] = S0+S1+bb;      // w == WID-1
}

// ---------------- column map for A6 (spaced_style 32ch + label 80ch), includes bias ----------------
__global__ void map6_kernel(const float* __restrict__ spaced,  // (128,2,32)
                            const float* __restrict__ label,   // (128,2,80)
                            const float* __restrict__ wgt,     // (128,240,3,3)
                            const float* __restrict__ bias,
                            float* __restrict__ mapv){         // (2,128,128)
  int n = blockIdx.x*256 + threadIdx.x;   // 32768
  int w = n & 127, o = (n >> 7) & 127, b = n >> 14;
  float a = bias[o];
  #pragma unroll
  for (int t=0;t<3;t++){
    int j = w + t - 1;
    if (j < 0 || j >= 128) continue;
    const float* sp = spaced + (j*2 + b)*32;
    const float* lb = label + (j*2 + b)*80;
    for (int c=0;c<32;c++){
      const float* wq = wgt + ((size_t)o*240 + 128 + c)*9 + t;
      a += sp[c]*(wq[0]+wq[3]+wq[6]);
    }
    for (int c=0;c<80;c++){
      const float* wq = wgt + ((size_t)o*240 + 160 + c)*9 + t;
      a += lb[c]*(wq[0]+wq[3]+wq[6]);
    }
  }
  mapv[n] = a;
}

// ---------------- 2x2 mean pool ----------------
__global__ void pool2_kernel(const float* __restrict__ in, float* __restrict__ out,
                             int H, int W, int total){
  int n = blockIdx.x*256 + threadIdx.x;
  if (n >= total) return;
  int Wo = W >> 1;
  int wo = n % Wo;
  int r = n / Wo;
  int Ho = H >> 1;
  int ho = r % Ho;
  int bc = r / Ho;
  const float* p = in + (bc*H + 2*ho)*W + 2*wo;
  out[n] = 0.25f*(p[0] + p[1] + p[W] + p[W+1]);
}

// ---------------- pM: one block per output (b,w); 256 threads = input channels ----------------
__global__ __launch_bounds__(256) void fm_kernel(const float* __restrict__ A7,
                          const float* __restrict__ fw,   // (1,256,3,3)
                          const float* __restrict__ fb,
                          float* __restrict__ out){
  __shared__ float red[4];
  int n = blockIdx.x;      // 0..127
  int b = n >> 6, w = n & 63;
  int c = threadIdx.x;     // 0..255
  float a = 0.f;
  #pragma unroll
  for (int r=0;r<3;r++){
    const float* ip = A7 + ((b*256+c)*3+r)*64;
    const float* wp = fw + (c*3+r)*3;
    #pragma unroll
    for (int kw=0;kw<3;kw++){
      int wi = w + kw - 1;
      if (wi>=0 && wi<64) a += ip[wi]*wp[kw];
    }
  }
  #pragma unroll
  for (int off=32; off>0; off>>=1) a += __shfl_down(a, off, 64);
  if ((threadIdx.x & 63) == 0) red[threadIdx.x>>6] = a;
  __syncthreads();
  if (threadIdx.x == 0) out[n] = red[0]+red[1]+red[2]+red[3] + fb[0];
}

// ---------------- char discriminator: one block per n=(b,t), 256 threads ----------------
__global__ __launch_bounds__(256) void cd_kernel(
    const float* __restrict__ A7,     // (2,256,3,64)
    const int*   __restrict__ clsb,   // (256)
    const float* __restrict__ Wc,     // (80,128,2304)
    const float* __restrict__ bc,     // (80,128)
    const float* __restrict__ cstyle, // (2,80,32)
    const float* __restrict__ W1,     // (80,160,128)
    const float* __restrict__ b1,     // (80,128)
    const float* __restrict__ W2,     // (80,128,1)
    const float* __restrict__ b2,     // (80,1)
    float* __restrict__ pChar)        // (256)
{
  __shared__ float patch[256*15];
  __shared__ float part[128*3];
  __shared__ float feat[160];
  __shared__ float red2[2];
  int n = blockIdx.x, tid = threadIdx.x;
  int b = n >> 7, t = n & 127;
  int e = clsb[n];
  int idx = t >> 1;

  for (int i=tid; i<3840; i+=256){
    int c = i/15, rj = i%15, r = rj/5, j = rj%5;
    int wc = idx - 2 + j;
    patch[i] = (wc >= 0 && wc < 64) ? A7[((b*256+c)*3+r)*64 + wc] : 0.f;
  }
  __syncthreads();

  int o = tid & 127, half = tid >> 7;
  float a0=0.f, a1=0.f, a2=0.f;
  const float* wp = Wc + ((size_t)e*128 + o)*2304 + half*128*9;
  const float* pbase = patch + half*128*15;
  for (int c=0;c<128;c++){
    #pragma unroll
    for (int r=0;r<3;r++){
      const float* pp = pbase + c*15 + r*5;
      const float* wq = wp + (c*3+r)*3;
      float w0=wq[0], w1=wq[1], w2=wq[2];
      float p0=pp[0], p1=pp[1], p2=pp[2], p3=pp[3], p4=pp[4];
      a0 += p0*w0 + p1*w1 + p2*w2;
      a1 += p1*w0 + p2*w1 + p3*w2;
      a2 += p2*w0 + p3*w1 + p4*w2;
    }
  }
  if (half == 1){ part[o*3] = a0; part[o*3+1] = a1; part[o*3+2] = a2; }
  __syncthreads();
  if (half == 0){
    a0 += part[o*3]; a1 += part[o*3+1]; a2 += part[o*3+2];
    float bb = bc[e*128 + o];
    a0 += bb; a1 += bb; a2 += bb;
    float pooled = (lrelu(a0)+lrelu(a1)+lrelu(a2)) * (1.f/3.f);
    feat[o] = pooled;
  }
  if (tid >= 128 && tid < 160) feat[128 + (tid-128)] = cstyle[(b*80 + e)*32 + (tid-128)];
  __syncthreads();

  float contrib = 0.f;
  if (half == 0){
    float s = b1[e*128 + o];
    for (int d=0;d<160;d++) s += feat[d]*W1[(e*160 + d)*128 + o];
    float h = s > 0.f ? s : 0.f;
    contrib = h * W2[e*128 + o];
    #pragma unroll
    for (int off=32; off>0; off>>=1) contrib += __shfl_down(contrib, off, 64);
    if ((tid & 63) == 0) red2[tid>>6] = contrib;
  }
  __syncthreads();
  if (tid == 0) pChar[n] = red2[0] + red2[1] + b2[e];
}

// ---------------- chain runner ----------------
template<int SA2,int SA4,int SA5,int SA6,int SA7>
static void run_chain(const float* x, const float* label, const float* g_style,
                      const float* spaced, const float* cstyle,
                      const float* sp1, const float* sp2,
                      const float* in_w, const float* in_b,
                      const float* c1w1, const float* c1b1,
                      const float* c1w2, const float* c1b2,
                      const float* c2w,  const float* c2b,
                      const float* c3w1, const float* c3b1,
                      const float* c3w2, const float* c3b2,
                      const float* fm_w, const float* fm_b,
                      const float* cdw,  const float* cdb,
                      const float* fc1w, const float* fc1b,
                      const float* fc2w, const float* fc2b,
                      float* out, char* ws, size_t r1_off, size_t tail_off,
                      hipStream_t stream){
  float* R0 = (float*)ws;
  float* R1 = (float*)(ws + r1_off);
  float* tail = (float*)(ws + tail_off);
  float* map6 = tail;            // 32768
  float* map1 = tail + 32768;    // 384
  float* map2 = tail + 33152;    // 768
  float* s1   = tail + 33920;    // 64
  float* s2   = tail + 33984;    // 128
  int*   clsb = (int*)(tail + 34112);  // 256

  style_kernel<<<1,256,0,stream>>>(g_style, sp1, sp2, s1, s2);
  cls_kernel<<<1,256,0,stream>>>(label, clsb);
  map3_kernel<32,96,64,64><<<1,128,0,stream>>>(s1, c1w1, c1b1, map1);
  map3_kernel<64,192,128,128><<<1,256,0,stream>>>(s2, c2w, c2b, map2);
  map6_kernel<<<128,256,0,stream>>>(spaced, label, c3w1, c3b1, map6);

  // h1 (2,64,58,512) -> R1
  conv_in_kernel<<<dim3(116,8,2),256,0,stream>>>(x, in_w, in_b, R1);
  // A2: main over 64ch -> R0 partials; combine w/ map1
  conv3_main<64,96,58,512,64,8,2,SA2><<<dim3(56,8*SA2,2),256,0,stream>>>(R1, c1w1, R0);
  combine_kernel<SA2,1,64,56,512><<<3584,256,0,stream>>>(R0, map1, nullptr);
  // P3 (2,64,28,256) -> R1
  pool2_kernel<<<3584,256,0,stream>>>(R0, R1, 56, 512, 917504);
  // A4: main 64ch -> R0 partials; combine bias
  conv3_main<64,64,28,256,128,8,2,SA4><<<dim3(13,16*SA4,2),256,0,stream>>>(R1, c1w2, R0);
  combine_kernel<SA4,0,128,26,256><<<1664,256,0,stream>>>(R0, nullptr, c1b2);
  // A5: main 128ch -> R1 partials; combine w/ map2
  conv3_main<128,192,26,256,128,8,2,SA5><<<dim3(12,16*SA5,2),256,0,stream>>>(R0, c2w, R1);
  combine_kernel<SA5,1,128,24,256><<<1536,256,0,stream>>>(R1, map2, nullptr);
  // P5 (2,128,12,128) -> R0
  pool2_kernel<<<1536,256,0,stream>>>(R1, R0, 24, 256, 393216);
  // A6: main 128ch -> R1 partials; combine w/ map6
  conv3_main<128,240,12,128,128,8,1,SA6><<<dim3(5,16*SA6,2),256,0,stream>>>(R0, c3w1, R1);
  combine_kernel<SA6,2,128,10,128><<<320,256,0,stream>>>(R1, map6, nullptr);
  // P6 (2,128,5,64) -> R0
  pool2_kernel<<<320,256,0,stream>>>(R1, R0, 10, 128, 81920);
  // A7: main 128ch -> R1 partials; combine bias
  conv3_main<128,128,5,64,256,4,1,SA7><<<dim3(1,64*SA7,2),256,0,stream>>>(R0, c3w2, R1);
  combine_kernel<SA7,0,256,3,64><<<96,256,0,stream>>>(R1, nullptr, c3b2);
  // pM -> out[0..128)
  fm_kernel<<<128,256,0,stream>>>(R1, fm_w, fm_b, out);
  // pChar -> out[128..384)
  cd_kernel<<<256,256,0,stream>>>(R1, clsb, cdw, cdb, cstyle, fc1w, fc1b, fc2w, fc2b, out + 128);
}

extern "C" void kernel_launch(void* const* d_in, const int* in_sizes, int n_in,
                              void* d_out, int out_size, void* d_ws, size_t ws_size,
                              hipStream_t stream){
  (void)in_sizes; (void)n_in; (void)out_size;
  const float* x      = (const float*)d_in[0];
  const float* label  = (const float*)d_in[1];
  const float* g_style= (const float*)d_in[2];
  const float* spaced = (const float*)d_in[3];
  const float* cstyle = (const float*)d_in[4];
  const float* sp1    = (const float*)d_in[5];
  const float* sp2    = (const float*)d_in[6];
  const float* in_w   = (const float*)d_in[7];
  const float* in_b   = (const float*)d_in[8];
  const float* c1w1   = (const float*)d_in[9];
  const float* c1b1   = (const float*)d_in[10];
  const float* c1w2   = (const float*)d_in[11];
  const float* c1b2   = (const float*)d_in[12];
  const float* c2w    = (const float*)d_in[13];
  const float* c2b    = (const float*)d_in[14];
  const float* c3w1   = (const float*)d_in[15];
  const float* c3b1   = (const float*)d_in[16];
  const float* c3w2   = (const float*)d_in[17];
  const float* c3b2   = (const float*)d_in[18];
  const float* fm_w   = (const float*)d_in[19];
  const float* fm_b   = (const float*)d_in[20];
  const float* cdw    = (const float*)d_in[21];
  const float* cdb    = (const float*)d_in[22];
  const float* fc1w   = (const float*)d_in[23];
  const float* fc1b   = (const float*)d_in[24];
  const float* fc2w   = (const float*)d_in[25];
  const float* fc2b   = (const float*)d_in[26];
  float* out = (float*)d_out;
  char* ws = (char*)d_ws;

  if (ws_size >= 56000000ULL){
    // big: R0 = 29,360,128 B (A2 partials x2), tail 147,456 B, R1 = 25,165,824 B (A5 partials x4)
    run_chain<2,4,4,8,8>(x,label,g_style,spaced,cstyle,sp1,sp2,in_w,in_b,c1w1,c1b1,c1w2,c1b2,
                         c2w,c2b,c3w1,c3b1,c3w2,c3b2,fm_w,fm_b,cdw,cdb,fc1w,fc1b,fc2w,fc2b,
                         out, ws, 29507584ULL, 29360128ULL, stream);
  } else {
    // small (<31 MB): R0 = 14,680,064 B, tail 147,456 B, R1 = 15,204,352 B (h1)
    run_chain<1,2,2,4,4>(x,label,g_style,spaced,cstyle,sp1,sp2,in_w,in_b,c1w1,c1b1,c1w2,c1b2,
                         c2w,c2b,c3w1,c3b1,c3w2,c3b2,fm_w,fm_b,cdw,cdb,fc1w,fc1b,fc2w,fc2b,
                         out, ws, 14827520ULL, 14680064ULL, stream);
  }
}

// Round 4
// 409.542 us; speedup vs baseline: 2.4787x; 1.0081x over previous
//
#include <hip/hip_runtime.h>

#define LEAKC 0.1f

__device__ __forceinline__ float lrelu(float v){ return v > 0.f ? v : LEAKC*v; }

// ---------------- styles: style1=(2,32), style2=(2,64) ----------------
__global__ void style_kernel(const float* __restrict__ g,
                             const float* __restrict__ sp1,
                             const float* __restrict__ sp2,
                             float* __restrict__ s1, float* __restrict__ s2){
  int t = threadIdx.x;
  if (t < 64){
    int b = t >> 5, j = t & 31;
    float a = 0.f;
    for (int k=0;k<256;k++) a += g[b*256+k]*sp1[j*256+k];
    s1[t] = a;
  } else if (t < 192){
    int u = t - 64;
    int b = u >> 6, j = u & 63;
    float a = 0.f;
    for (int k=0;k<256;k++) a += g[b*256+k]*sp2[j*256+k];
    s2[u] = a;
  }
}

// ---------------- cls[b,t] = argmax_c label[t,b,c] ----------------
__global__ void cls_kernel(const float* __restrict__ label, int* __restrict__ cls){
  int n = threadIdx.x;              // 0..255, n = b*128 + t
  int b = n >> 7, t = n & 127;
  const float* p = label + (t*2 + b)*80;
  float best = p[0]; int bi = 0;
  for (int c=1;c<80;c++){ float v = p[c]; if (v > best){ best = v; bi = c; } }
  cls[n] = bi;
}

// ---------------- input conv 7x7, pad(0,3): x(2,1,64,512) -> (2,64,58,512), lrelu ----------------
__global__ void conv_in_kernel(const float* __restrict__ x,
                               const float* __restrict__ wgt,   // (64,1,7,7)
                               const float* __restrict__ bias,
                               float* __restrict__ out){
  int hw = blockIdx.x*256 + threadIdx.x;   // < 58*512 = 29696
  int y = hw >> 9, w = hw & 511;
  int b = blockIdx.z;
  int o0 = blockIdx.y * 8;
  float acc[8];
  #pragma unroll
  for (int i=0;i<8;i++) acc[i] = bias[o0+i];
  for (int kh=0;kh<7;kh++){
    const float* ip = x + (b*64 + y + kh)*512;
    #pragma unroll
    for (int kw=0;kw<7;kw++){
      int wi = w + kw - 3;
      float v = (wi>=0 && wi<512) ? ip[wi] : 0.f;
      #pragma unroll
      for (int i=0;i<8;i++) acc[i] += v * wgt[(o0+i)*49 + kh*7 + kw];
    }
  }
  #pragma unroll
  for (int i=0;i<8;i++)
    out[((b*64 + o0+i)*58 + y)*512 + w] = lrelu(acc[i]);
}

// ---------------- main 3x3 conv over CM real channels, K-split partials ----------------
template<int CM,int CTOT,int HIN,int WID,int COUT,int OPT,int PW,int SPLIT>
__global__ void conv3_main(const float* __restrict__ in,
                           const float* __restrict__ wgt,   // (COUT, CTOT, 3, 3)
                           float* __restrict__ part){
  constexpr int HOUT = HIN - 2;
  constexpr int CSPLIT = CM / SPLIT;
  constexpr int N = 2*COUT*HOUT*WID;
  int hw0 = blockIdx.x*(256*PW) + threadIdx.x*PW;
  if (hw0 >= HOUT*WID) return;
  int y = hw0 / WID, w0 = hw0 % WID;
  int b = blockIdx.z;
  int yy = blockIdx.y;
  int split = yy % SPLIT;
  int o0 = (yy / SPLIT) * OPT;

  float acc[OPT][PW];
  #pragma unroll
  for (int i=0;i<OPT;i++)
    #pragma unroll
    for (int p=0;p<PW;p++) acc[i][p] = 0.f;

  const bool lok = (w0 > 0), rok = (w0 + PW) < WID;
  int c0 = split * CSPLIT;
  for (int c=c0; c<c0+CSPLIT; c++){
    const float* rp = in + ((b*CM + c)*HIN + y)*WID + w0;
    #pragma unroll
    for (int kh=0;kh<3;kh++){
      float v[PW+2];
      v[0] = lok ? rp[kh*WID - 1] : 0.f;
      #pragma unroll
      for (int j=0;j<PW;j++) v[1+j] = rp[kh*WID + j];
      v[PW+1] = rok ? rp[kh*WID + PW] : 0.f;
      #pragma unroll
      for (int i=0;i<OPT;i++){
        const float* wq = wgt + ((size_t)(o0+i)*CTOT + c)*9 + kh*3;
        float w0c=wq[0], w1c=wq[1], w2c=wq[2];
        #pragma unroll
        for (int p=0;p<PW;p++)
          acc[i][p] += v[p]*w0c + v[p+1]*w1c + v[p+2]*w2c;
      }
    }
  }
  #pragma unroll
  for (int i=0;i<OPT;i++){
    int base = split*N + ((b*COUT + o0+i)*HOUT + y)*WID + w0;
    #pragma unroll
    for (int p=0;p<PW;p++) part[base+p] = acc[i][p];
  }
}

// ---------------- combine partials + additive map + lrelu ----------------
template<int SPLIT,int MODE,int COUT,int HOUT,int WID>
__global__ __launch_bounds__(256) void combine_kernel(float* __restrict__ part,
                                                      const float* __restrict__ mapv,
                                                      const float* __restrict__ bias){
  constexpr int N = 2*COUT*HOUT*WID;
  int idx = (blockIdx.x*256 + threadIdx.x)*4;
  if (idx >= N) return;
  float4 v = *(float4*)(part + idx);
  #pragma unroll
  for (int s=1;s<SPLIT;s++){
    float4 u = *(const float4*)(part + (size_t)s*N + idx);
    v.x += u.x; v.y += u.y; v.z += u.z; v.w += u.w;
  }
  int w = idx % WID;
  int r = idx / WID;
  int bo = r / HOUT;
  int o = bo % COUT, b = bo / COUT;
  float* av = (float*)&v;
  if (MODE == 0){
    float bb = bias[o];
    #pragma unroll
    for (int j=0;j<4;j++) av[j] += bb;
  } else if (MODE == 1){
    const float* m = mapv + (size_t)(b*COUT + o)*3;
    #pragma unroll
    for (int j=0;j<4;j++){
      int wj = w + j;
      av[j] += (wj == 0) ? m[0] : ((wj == WID-1) ? m[2] : m[1]);
    }
  } else {
    const float* m = mapv + ((size_t)(b*COUT + o))*WID + w;
    #pragma unroll
    for (int j=0;j<4;j++) av[j] += m[j];
  }
  #pragma unroll
  for (int j=0;j<4;j++) av[j] = lrelu(av[j]);
  *(float4*)(part + idx) = v;
}

// ---------------- 3-value style map (broadcast style channels) ----------------
template<int CS,int CTOT,int COUT,int COFF>
__global__ void map3_kernel(const float* __restrict__ style,  // (2,CS)
                            const float* __restrict__ wgt,    // (COUT,CTOT,3,3)
                            const float* __restrict__ bias,
                            float* __restrict__ mapv){        // (2,COUT,3)
  int t = threadIdx.x;
  if (t >= 2*COUT) return;
  int b = t / COUT, o = t % COUT;
  float S0=0.f, S1=0.f, S2=0.f;
  for (int c=0;c<CS;c++){
    float s = style[b*CS + c];
    const float* wq = wgt + ((size_t)o*CTOT + COFF + c)*9;
    S0 += s*(wq[0]+wq[3]+wq[6]);
    S1 += s*(wq[1]+wq[4]+wq[7]);
    S2 += s*(wq[2]+wq[5]+wq[8]);
  }
  float bb = bias[o];
  mapv[t*3+0] = S1+S2+bb;      // w == 0
  mapv[t*3+1] = S0+S1+S2+bb;   // interior
  mapv[t*3+2] = S0+S1+bb;      // w == WID-1
}

// ---------------- column map for A6 (spaced_style 32ch + label 80ch), includes bias ----------------
__global__ void map6_kernel(const float* __restrict__ spaced,  // (128,2,32)
                            const float* __restrict__ label,   // (128,2,80)
                            const float* __restrict__ wgt,     // (128,240,3,3)
                            const float* __restrict__ bias,
                            float* __restrict__ mapv){         // (2,128,128)
  int n = blockIdx.x*256 + threadIdx.x;   // 32768
  int w = n & 127, o = (n >> 7) & 127, b = n >> 14;
  float a = bias[o];
  #pragma unroll
  for (int t=0;t<3;t++){
    int j = w + t - 1;
    if (j < 0 || j >= 128) continue;
    const float* sp = spaced + (j*2 + b)*32;
    const float* lb = label + (j*2 + b)*80;
    for (int c=0;c<32;c++){
      const float* wq = wgt + ((size_t)o*240 + 128 + c)*9 + t;
      a += sp[c]*(wq[0]+wq[3]+wq[6]);
    }
    for (int c=0;c<80;c++){
      const float* wq = wgt + ((size_t)o*240 + 160 + c)*9 + t;
      a += lb[c]*(wq[0]+wq[3]+wq[6]);
    }
  }
  mapv[n] = a;
}

// ---------------- 2x2 mean pool ----------------
__global__ void pool2_kernel(const float* __restrict__ in, float* __restrict__ out,
                             int H, int W, int total){
  int n = blockIdx.x*256 + threadIdx.x;
  if (n >= total) return;
  int Wo = W >> 1;
  int wo = n % Wo;
  int r = n / Wo;
  int Ho = H >> 1;
  int ho = r % Ho;
  int bc = r / Ho;
  const float* p = in + (bc*H + 2*ho)*W + 2*wo;
  out[n] = 0.25f*(p[0] + p[1] + p[W] + p[W+1]);
}

// ---------------- pM: one block per output (b,w); 256 threads = input channels ----------------
__global__ __launch_bounds__(256) void fm_kernel(const float* __restrict__ A7,
                          const float* __restrict__ fw,   // (1,256,3,3)
                          const float* __restrict__ fb,
                          float* __restrict__ out){
  __shared__ float red[4];
  int n = blockIdx.x;      // 0..127
  int b = n >> 6, w = n & 63;
  int c = threadIdx.x;     // 0..255
  float a = 0.f;
  #pragma unroll
  for (int r=0;r<3;r++){
    const float* ip = A7 + ((b*256+c)*3+r)*64;
    const float* wp = fw + (c*3+r)*3;
    #pragma unroll
    for (int kw=0;kw<3;kw++){
      int wi = w + kw - 1;
      if (wi>=0 && wi<64) a += ip[wi]*wp[kw];
    }
  }
  #pragma unroll
  for (int off=32; off>0; off>>=1) a += __shfl_down(a, off, 64);
  if ((threadIdx.x & 63) == 0) red[threadIdx.x>>6] = a;
  __syncthreads();
  if (threadIdx.x == 0) out[n] = red[0]+red[1]+red[2]+red[3] + fb[0];
}

// ---------------- cd conv partials: one block per (sample, channel-quarter) ----------------
// part layout: [q][n][o][3]
__global__ __launch_bounds__(256) void cd_conv_kernel(
    const float* __restrict__ A7,     // (2,256,3,64)
    const int*   __restrict__ clsb,   // (256)
    const float* __restrict__ Wc,     // (80,128,2304)
    float* __restrict__ part)         // (4,256,128,3)
{
  __shared__ float patch[64*15];
  __shared__ float red[128*3];
  int blk = blockIdx.x;     // 0..1023
  int n = blk >> 2, q = blk & 3;
  int b = n >> 7, t = n & 127;
  int e = clsb[n];
  int idx = t >> 1;
  int tid = threadIdx.x;
  int c0 = q * 64;

  for (int i=tid; i<64*15; i+=256){
    int c = i/15, rj = i%15, r = rj/5, j = rj%5;
    int wc = idx - 2 + j;
    patch[i] = (wc >= 0 && wc < 64) ? A7[((b*256+c0+c)*3+r)*64 + wc] : 0.f;
  }
  __syncthreads();

  int o = tid & 127, half = tid >> 7;
  int cbeg = half * 32;     // within the 64-channel window
  const float4* wp4 = (const float4*)(Wc + ((size_t)e*128 + o)*2304 + (size_t)(c0+cbeg)*9);
  const float* pb = patch + cbeg*15;
  float a0=0.f, a1=0.f, a2=0.f;
  // 8 groups of 4 channels; 36 weights = 9 float4 per group
  for (int g=0; g<8; ++g){
    float wv[36];
    #pragma unroll
    for (int j=0;j<9;j++) *(float4*)(wv + 4*j) = wp4[j];
    wp4 += 9;
    const float* pp = pb + g*60;
    #pragma unroll
    for (int c=0;c<4;c++){
      #pragma unroll
      for (int r=0;r<3;r++){
        const float* pp2 = pp + c*15 + r*5;
        float W0=wv[c*9+r*3], W1=wv[c*9+r*3+1], W2=wv[c*9+r*3+2];
        float p0=pp2[0], p1=pp2[1], p2=pp2[2], p3=pp2[3], p4=pp2[4];
        a0 += p0*W0 + p1*W1 + p2*W2;
        a1 += p1*W0 + p2*W1 + p3*W2;
        a2 += p2*W0 + p3*W1 + p4*W2;
      }
    }
  }
  if (half == 1){ red[o*3]=a0; red[o*3+1]=a1; red[o*3+2]=a2; }
  __syncthreads();
  if (half == 0){
    float* pp = part + (((size_t)q*256 + n)*128 + o)*3;
    pp[0] = a0 + red[o*3];
    pp[1] = a1 + red[o*3+1];
    pp[2] = a2 + red[o*3+2];
  }
}

// ---------------- cd tail: combine partials, pool, fc1, fc2 ----------------
__global__ __launch_bounds__(128) void cd_tail_kernel(
    const float* __restrict__ part,   // (4,256,128,3)
    const int*   __restrict__ clsb,
    const float* __restrict__ bcv,    // (80,128)
    const float* __restrict__ cstyle, // (2,80,32)
    const float* __restrict__ W1,     // (80,160,128)
    const float* __restrict__ b1,     // (80,128)
    const float* __restrict__ W2,     // (80,128,1)
    const float* __restrict__ b2,     // (80,1)
    float* __restrict__ pChar)        // (256)
{
  __shared__ float feat[160];
  __shared__ float red2[2];
  int n = blockIdx.x, tid = threadIdx.x;
  int b = n >> 7;
  int e = clsb[n];
  int o = tid;
  float a0=0.f, a1=0.f, a2=0.f;
  #pragma unroll
  for (int q=0;q<4;q++){
    const float* p = part + (((size_t)q*256 + n)*128 + o)*3;
    a0 += p[0]; a1 += p[1]; a2 += p[2];
  }
  float bb = bcv[e*128 + o];
  a0 += bb; a1 += bb; a2 += bb;
  feat[o] = (lrelu(a0)+lrelu(a1)+lrelu(a2)) * (1.f/3.f);
  if (tid < 32) feat[128+tid] = cstyle[(b*80 + e)*32 + tid];
  __syncthreads();

  float s = b1[e*128 + o];
  for (int d=0;d<160;d++) s += feat[d]*W1[(e*160 + d)*128 + o];
  float h = s > 0.f ? s : 0.f;
  float contrib = h * W2[e*128 + o];
  #pragma unroll
  for (int off=32; off>0; off>>=1) contrib += __shfl_down(contrib, off, 64);
  if ((tid & 63) == 0) red2[tid>>6] = contrib;
  __syncthreads();
  if (tid == 0) pChar[n] = red2[0] + red2[1] + b2[e];
}

// ---------------- chain runner ----------------
template<int SA2,int SA4,int SA5,int SA6,int SA7>
static void run_chain(const float* x, const float* label, const float* g_style,
                      const float* spaced, const float* cstyle,
                      const float* sp1, const float* sp2,
                      const float* in_w, const float* in_b,
                      const float* c1w1, const float* c1b1,
                      const float* c1w2, const float* c1b2,
                      const float* c2w,  const float* c2b,
                      const float* c3w1, const float* c3b1,
                      const float* c3w2, const float* c3b2,
                      const float* fm_w, const float* fm_b,
                      const float* cdw,  const float* cdb,
                      const float* fc1w, const float* fc1b,
                      const float* fc2w, const float* fc2b,
                      float* out, char* ws, size_t r1_off, size_t tail_off,
                      hipStream_t stream){
  float* R0 = (float*)ws;
  float* R1 = (float*)(ws + r1_off);
  float* tail = (float*)(ws + tail_off);
  float* map6 = tail;            // 32768
  float* map1 = tail + 32768;    // 384
  float* map2 = tail + 33152;    // 768
  float* s1   = tail + 33920;    // 64
  float* s2   = tail + 33984;    // 128
  int*   clsb = (int*)(tail + 34112);  // 256
  float* cdp  = R0 + 524288;     // cd partials: 393216 floats (1.5 MB) at +2 MB into R0

  style_kernel<<<1,256,0,stream>>>(g_style, sp1, sp2, s1, s2);
  cls_kernel<<<1,256,0,stream>>>(label, clsb);
  map3_kernel<32,96,64,64><<<1,128,0,stream>>>(s1, c1w1, c1b1, map1);
  map3_kernel<64,192,128,128><<<1,256,0,stream>>>(s2, c2w, c2b, map2);
  map6_kernel<<<128,256,0,stream>>>(spaced, label, c3w1, c3b1, map6);

  // h1 (2,64,58,512) -> R1
  conv_in_kernel<<<dim3(116,8,2),256,0,stream>>>(x, in_w, in_b, R1);
  // A2: main over 64ch -> R0 partials; combine w/ map1
  conv3_main<64,96,58,512,64,8,2,SA2><<<dim3(56,8*SA2,2),256,0,stream>>>(R1, c1w1, R0);
  combine_kernel<SA2,1,64,56,512><<<3584,256,0,stream>>>(R0, map1, nullptr);
  // P3 (2,64,28,256) -> R1
  pool2_kernel<<<3584,256,0,stream>>>(R0, R1, 56, 512, 917504);
  // A4: main 64ch -> R0 partials; combine bias
  conv3_main<64,64,28,256,128,8,2,SA4><<<dim3(13,16*SA4,2),256,0,stream>>>(R1, c1w2, R0);
  combine_kernel<SA4,0,128,26,256><<<1664,256,0,stream>>>(R0, nullptr, c1b2);
  // A5: main 128ch -> R1 partials; combine w/ map2
  conv3_main<128,192,26,256,128,8,2,SA5><<<dim3(12,16*SA5,2),256,0,stream>>>(R0, c2w, R1);
  combine_kernel<SA5,1,128,24,256><<<1536,256,0,stream>>>(R1, map2, nullptr);
  // P5 (2,128,12,128) -> R0
  pool2_kernel<<<1536,256,0,stream>>>(R1, R0, 24, 256, 393216);
  // A6: main 128ch -> R1 partials; combine w/ map6
  conv3_main<128,240,12,128,128,8,1,SA6><<<dim3(5,16*SA6,2),256,0,stream>>>(R0, c3w1, R1);
  combine_kernel<SA6,2,128,10,128><<<320,256,0,stream>>>(R1, map6, nullptr);
  // P6 (2,128,5,64) -> R0
  pool2_kernel<<<320,256,0,stream>>>(R1, R0, 10, 128, 81920);
  // A7: main 128ch -> R1 partials; combine bias
  conv3_main<128,128,5,64,256,4,1,SA7><<<dim3(1,64*SA7,2),256,0,stream>>>(R0, c3w2, R1);
  combine_kernel<SA7,0,256,3,64><<<96,256,0,stream>>>(R1, nullptr, c3b2);
  // pM -> out[0..128)
  fm_kernel<<<128,256,0,stream>>>(R1, fm_w, fm_b, out);
  // pChar: split conv partials then tail
  cd_conv_kernel<<<1024,256,0,stream>>>(R1, clsb, cdw, cdp);
  cd_tail_kernel<<<256,128,0,stream>>>(cdp, clsb, cdb, cstyle, fc1w, fc1b, fc2w, fc2b, out + 128);
}

extern "C" void kernel_launch(void* const* d_in, const int* in_sizes, int n_in,
                              void* d_out, int out_size, void* d_ws, size_t ws_size,
                              hipStream_t stream){
  (void)in_sizes; (void)n_in; (void)out_size;
  const float* x      = (const float*)d_in[0];
  const float* label  = (const float*)d_in[1];
  const float* g_style= (const float*)d_in[2];
  const float* spaced = (const float*)d_in[3];
  const float* cstyle = (const float*)d_in[4];
  const float* sp1    = (const float*)d_in[5];
  const float* sp2    = (const float*)d_in[6];
  const float* in_w   = (const float*)d_in[7];
  const float* in_b   = (const float*)d_in[8];
  const float* c1w1   = (const float*)d_in[9];
  const float* c1b1   = (const float*)d_in[10];
  const float* c1w2   = (const float*)d_in[11];
  const float* c1b2   = (const float*)d_in[12];
  const float* c2w    = (const float*)d_in[13];
  const float* c2b    = (const float*)d_in[14];
  const float* c3w1   = (const float*)d_in[15];
  const float* c3b1   = (const float*)d_in[16];
  const float* c3w2   = (const float*)d_in[17];
  const float* c3b2   = (const float*)d_in[18];
  const float* fm_w   = (const float*)d_in[19];
  const float* fm_b   = (const float*)d_in[20];
  const float* cdw    = (const float*)d_in[21];
  const float* cdb    = (const float*)d_in[22];
  const float* fc1w   = (const float*)d_in[23];
  const float* fc1b   = (const float*)d_in[24];
  const float* fc2w   = (const float*)d_in[25];
  const float* fc2b   = (const float*)d_in[26];
  float* out = (float*)d_out;
  char* ws = (char*)d_ws;

  if (ws_size >= 56000000ULL){
    run_chain<2,4,4,8,8>(x,label,g_style,spaced,cstyle,sp1,sp2,in_w,in_b,c1w1,c1b1,c1w2,c1b2,
                         c2w,c2b,c3w1,c3b1,c3w2,c3b2,fm_w,fm_b,cdw,cdb,fc1w,fc1b,fc2w,fc2b,
                         out, ws, 29507584ULL, 29360128ULL, stream);
  } else {
    run_chain<1,2,2,4,4>(x,label,g_style,spaced,cstyle,sp1,sp2,in_w,in_b,c1w1,c1b1,c1w2,c1b2,
                         c2w,c2b,c3w1,c3b1,c3w2,c3b2,fm_w,fm_b,cdw,cdb,fc1w,fc1b,fc2w,fc2b,
                         out, ws, 14827520ULL, 14680064ULL, stream);
  }
}

// Round 5
// 403.597 us; speedup vs baseline: 2.5152x; 1.0147x over previous
//
#include <hip/hip_runtime.h>

#define LEAKC 0.1f

__device__ __forceinline__ float lrelu(float v){ return v > 0.f ? v : LEAKC*v; }

// ---------------- styles: style1=(2,32), style2=(2,64) ----------------
__global__ void style_kernel(const float* __restrict__ g,
                             const float* __restrict__ sp1,
                             const float* __restrict__ sp2,
                             float* __restrict__ s1, float* __restrict__ s2){
  int t = threadIdx.x;
  if (t < 64){
    int b = t >> 5, j = t & 31;
    float a = 0.f;
    for (int k=0;k<256;k++) a += g[b*256+k]*sp1[j*256+k];
    s1[t] = a;
  } else if (t < 192){
    int u = t - 64;
    int b = u >> 6, j = u & 63;
    float a = 0.f;
    for (int k=0;k<256;k++) a += g[b*256+k]*sp2[j*256+k];
    s2[u] = a;
  }
}

// ---------------- cls[b,t] = argmax_c label[t,b,c] ----------------
__global__ void cls_kernel(const float* __restrict__ label, int* __restrict__ cls){
  int n = threadIdx.x;              // 0..255, n = b*128 + t
  int b = n >> 7, t = n & 127;
  const float* p = label + (t*2 + b)*80;
  float best = p[0]; int bi = 0;
  for (int c=1;c<80;c++){ float v = p[c]; if (v > best){ best = v; bi = c; } }
  cls[n] = bi;
}

// ---------------- input conv 7x7, pad(0,3): x(2,1,64,512) -> (2,64,58,512), lrelu ----------------
__global__ void conv_in_kernel(const float* __restrict__ x,
                               const float* __restrict__ wgt,   // (64,1,7,7)
                               const float* __restrict__ bias,
                               float* __restrict__ out){
  int hw = blockIdx.x*256 + threadIdx.x;   // < 58*512 = 29696
  int y = hw >> 9, w = hw & 511;
  int b = blockIdx.z;
  int o0 = blockIdx.y * 8;
  float acc[8];
  #pragma unroll
  for (int i=0;i<8;i++) acc[i] = bias[o0+i];
  for (int kh=0;kh<7;kh++){
    const float* ip = x + (b*64 + y + kh)*512;
    #pragma unroll
    for (int kw=0;kw<7;kw++){
      int wi = w + kw - 3;
      float v = (wi>=0 && wi<512) ? ip[wi] : 0.f;
      #pragma unroll
      for (int i=0;i<8;i++) acc[i] += v * wgt[(o0+i)*49 + kh*7 + kw];
    }
  }
  #pragma unroll
  for (int i=0;i<8;i++)
    out[((b*64 + o0+i)*58 + y)*512 + w] = lrelu(acc[i]);
}

// ---------------- main 3x3 conv, PW=4 with float4 input loads, K-split partials ----------------
template<int CM,int CTOT,int HIN,int WID,int COUT,int OPT,int SPLIT>
__global__ void conv3_main4(const float* __restrict__ in,
                            const float* __restrict__ wgt,   // (COUT, CTOT, 3, 3)
                            float* __restrict__ part){
  constexpr int HOUT = HIN - 2;
  constexpr int CSPLIT = CM / SPLIT;
  constexpr int N = 2*COUT*HOUT*WID;
  int hw0 = blockIdx.x*1024 + threadIdx.x*4;
  if (hw0 >= HOUT*WID) return;
  int y = hw0 / WID, w0 = hw0 % WID;
  int b = blockIdx.z;
  int split = blockIdx.y % SPLIT;
  int o0 = (blockIdx.y / SPLIT) * OPT;

  float acc[OPT][4];
  #pragma unroll
  for (int i=0;i<OPT;i++)
    #pragma unroll
    for (int p=0;p<4;p++) acc[i][p] = 0.f;

  const bool lok = (w0 > 0), rok = (w0 + 4) < WID;
  int c0 = split * CSPLIT;
  for (int c=c0; c<c0+CSPLIT; c++){
    const float* rp = in + ((size_t)(b*CM + c)*HIN + y)*WID + w0;
    #pragma unroll
    for (int kh=0;kh<3;kh++){
      float4 m = *(const float4*)(rp + kh*WID);
      float v[6];
      v[0] = lok ? rp[kh*WID - 1] : 0.f;
      v[1]=m.x; v[2]=m.y; v[3]=m.z; v[4]=m.w;
      v[5] = rok ? rp[kh*WID + 4] : 0.f;
      #pragma unroll
      for (int i=0;i<OPT;i++){
        const float* wq = wgt + ((size_t)(o0+i)*CTOT + c)*9 + kh*3;
        float W0=wq[0], W1=wq[1], W2=wq[2];
        #pragma unroll
        for (int p=0;p<4;p++)
          acc[i][p] += v[p]*W0 + v[p+1]*W1 + v[p+2]*W2;
      }
    }
  }
  #pragma unroll
  for (int i=0;i<OPT;i++){
    float* op = part + (size_t)split*N + ((size_t)(b*COUT + o0+i)*HOUT + y)*WID + w0;
    *(float4*)op = *(const float4*)acc[i];
  }
}

// ---------------- PW=1 variant for narrow layers (A6, A7) ----------------
template<int CM,int CTOT,int HIN,int WID,int COUT,int OPT,int SPLIT>
__global__ void conv3_main1(const float* __restrict__ in,
                            const float* __restrict__ wgt,
                            float* __restrict__ part){
  constexpr int HOUT = HIN - 2;
  constexpr int CSPLIT = CM / SPLIT;
  constexpr int N = 2*COUT*HOUT*WID;
  int hw0 = blockIdx.x*256 + threadIdx.x;
  if (hw0 >= HOUT*WID) return;
  int y = hw0 / WID, w0 = hw0 % WID;
  int b = blockIdx.z;
  int split = blockIdx.y % SPLIT;
  int o0 = (blockIdx.y / SPLIT) * OPT;

  float acc[OPT];
  #pragma unroll
  for (int i=0;i<OPT;i++) acc[i] = 0.f;

  const bool lok = (w0 > 0), rok = (w0 + 1) < WID;
  int c0 = split * CSPLIT;
  for (int c=c0; c<c0+CSPLIT; c++){
    const float* rp = in + ((size_t)(b*CM + c)*HIN + y)*WID + w0;
    #pragma unroll
    for (int kh=0;kh<3;kh++){
      float v0 = lok ? rp[kh*WID - 1] : 0.f;
      float v1 = rp[kh*WID];
      float v2 = rok ? rp[kh*WID + 1] : 0.f;
      #pragma unroll
      for (int i=0;i<OPT;i++){
        const float* wq = wgt + ((size_t)(o0+i)*CTOT + c)*9 + kh*3;
        acc[i] += v0*wq[0] + v1*wq[1] + v2*wq[2];
      }
    }
  }
  #pragma unroll
  for (int i=0;i<OPT;i++)
    part[(size_t)split*N + ((size_t)(b*COUT + o0+i)*HOUT + y)*WID + w0] = acc[i];
}

// ---------------- combine partials + additive map + lrelu ----------------
template<int SPLIT,int MODE,int COUT,int HOUT,int WID>
__global__ __launch_bounds__(256) void combine_kernel(float* __restrict__ part,
                                                      const float* __restrict__ mapv,
                                                      const float* __restrict__ bias){
  constexpr int N = 2*COUT*HOUT*WID;
  int idx = (blockIdx.x*256 + threadIdx.x)*4;
  if (idx >= N) return;
  float4 v = *(float4*)(part + idx);
  #pragma unroll
  for (int s=1;s<SPLIT;s++){
    float4 u = *(const float4*)(part + (size_t)s*N + idx);
    v.x += u.x; v.y += u.y; v.z += u.z; v.w += u.w;
  }
  int w = idx % WID;
  int r = idx / WID;
  int bo = r / HOUT;
  int o = bo % COUT, b = bo / COUT;
  float* av = (float*)&v;
  if (MODE == 0){
    float bb = bias[o];
    #pragma unroll
    for (int j=0;j<4;j++) av[j] += bb;
  } else if (MODE == 1){
    const float* m = mapv + (size_t)(b*COUT + o)*3;
    #pragma unroll
    for (int j=0;j<4;j++){
      int wj = w + j;
      av[j] += (wj == 0) ? m[0] : ((wj == WID-1) ? m[2] : m[1]);
    }
  } else {
    const float* m = mapv + ((size_t)(b*COUT + o))*WID + w;
    #pragma unroll
    for (int j=0;j<4;j++) av[j] += m[j];
  }
  #pragma unroll
  for (int j=0;j<4;j++) av[j] = lrelu(av[j]);
  *(float4*)(part + idx) = v;
}

// ---------------- 3-value style map (broadcast style channels) ----------------
template<int CS,int CTOT,int COUT,int COFF>
__global__ void map3_kernel(const float* __restrict__ style,  // (2,CS)
                            const float* __restrict__ wgt,    // (COUT,CTOT,3,3)
                            const float* __restrict__ bias,
                            float* __restrict__ mapv){        // (2,COUT,3)
  int t = threadIdx.x;
  if (t >= 2*COUT) return;
  int b = t / COUT, o = t % COUT;
  float S0=0.f, S1=0.f, S2=0.f;
  for (int c=0;c<CS;c++){
    float s = style[b*CS + c];
    const float* wq = wgt + ((size_t)o*CTOT + COFF + c)*9;
    S0 += s*(wq[0]+wq[3]+wq[6]);
    S1 += s*(wq[1]+wq[4]+wq[7]);
    S2 += s*(wq[2]+wq[5]+wq[8]);
  }
  float bb = bias[o];
  mapv[t*3+0] = S1+S2+bb;      // w == 0
  mapv[t*3+1] = S0+S1+S2+bb;   // interior
  mapv[t*3+2] = S0+S1+bb;      // w == WID-1
}

// ---------------- column map for A6 (spaced_style 32ch + label 80ch), includes bias ----------------
__global__ void map6_kernel(const float* __restrict__ spaced,  // (128,2,32)
                            const float* __restrict__ label,   // (128,2,80)
                            const float* __restrict__ wgt,     // (128,240,3,3)
                            const float* __restrict__ bias,
                            float* __restrict__ mapv){         // (2,128,128)
  int n = blockIdx.x*256 + threadIdx.x;   // 32768
  int w = n & 127, o = (n >> 7) & 127, b = n >> 14;
  float a = bias[o];
  #pragma unroll
  for (int t=0;t<3;t++){
    int j = w + t - 1;
    if (j < 0 || j >= 128) continue;
    const float* sp = spaced + (j*2 + b)*32;
    const float* lb = label + (j*2 + b)*80;
    for (int c=0;c<32;c++){
      const float* wq = wgt + ((size_t)o*240 + 128 + c)*9 + t;
      a += sp[c]*(wq[0]+wq[3]+wq[6]);
    }
    for (int c=0;c<80;c++){
      const float* wq = wgt + ((size_t)o*240 + 160 + c)*9 + t;
      a += lb[c]*(wq[0]+wq[3]+wq[6]);
    }
  }
  mapv[n] = a;
}

// ---------------- 2x2 mean pool ----------------
__global__ void pool2_kernel(const float* __restrict__ in, float* __restrict__ out,
                             int H, int W, int total){
  int n = blockIdx.x*256 + threadIdx.x;
  if (n >= total) return;
  int Wo = W >> 1;
  int wo = n % Wo;
  int r = n / Wo;
  int Ho = H >> 1;
  int ho = r % Ho;
  int bc = r / Ho;
  const float* p = in + (bc*H + 2*ho)*W + 2*wo;
  out[n] = 0.25f*(p[0] + p[1] + p[W] + p[W+1]);
}

// ---------------- pM: one block per output (b,w); 256 threads = input channels ----------------
__global__ __launch_bounds__(256) void fm_kernel(const float* __restrict__ A7,
                          const float* __restrict__ fw,   // (1,256,3,3)
                          const float* __restrict__ fb,
                          float* __restrict__ out){
  __shared__ float red[4];
  int n = blockIdx.x;      // 0..127
  int b = n >> 6, w = n & 63;
  int c = threadIdx.x;     // 0..255
  float a = 0.f;
  #pragma unroll
  for (int r=0;r<3;r++){
    const float* ip = A7 + ((b*256+c)*3+r)*64;
    const float* wp = fw + (c*3+r)*3;
    #pragma unroll
    for (int kw=0;kw<3;kw++){
      int wi = w + kw - 1;
      if (wi>=0 && wi<64) a += ip[wi]*wp[kw];
    }
  }
  #pragma unroll
  for (int off=32; off>0; off>>=1) a += __shfl_down(a, off, 64);
  if ((threadIdx.x & 63) == 0) red[threadIdx.x>>6] = a;
  __syncthreads();
  if (threadIdx.x == 0) out[n] = red[0]+red[1]+red[2]+red[3] + fb[0];
}

// ---------------- cd conv partials: one block per (sample, channel-eighth) ----------------
// part layout: [q][n][o][3], q in [0,8)
__global__ __launch_bounds__(256) void cd_conv_kernel(
    const float* __restrict__ A7,     // (2,256,3,64)
    const int*   __restrict__ clsb,   // (256)
    const float* __restrict__ Wc,     // (80,128,2304)
    float* __restrict__ part)         // (8,256,128,3)
{
  __shared__ float patch[32*15];
  __shared__ float red[128*3];
  int blk = blockIdx.x;     // 0..2047
  int n = blk >> 3, q = blk & 7;
  int b = n >> 7, t = n & 127;
  int e = clsb[n];
  int idx = t >> 1;
  int tid = threadIdx.x;
  int c0 = q * 32;

  for (int i=tid; i<32*15; i+=256){
    int c = i/15, rj = i%15, r = rj/5, j = rj%5;
    int wc = idx - 2 + j;
    patch[i] = (wc >= 0 && wc < 64) ? A7[((b*256+c0+c)*3+r)*64 + wc] : 0.f;
  }
  __syncthreads();

  int o = tid & 127, half = tid >> 7;
  int cbeg = half * 16;     // within the 32-channel window
  const float4* wp4 = (const float4*)(Wc + ((size_t)e*128 + o)*2304 + (size_t)(c0+cbeg)*9);
  const float* pb = patch + cbeg*15;
  float a0=0.f, a1=0.f, a2=0.f;
  // 4 groups of 4 channels; 36 weights = 9 float4 per group
  for (int g=0; g<4; ++g){
    float wv[36];
    #pragma unroll
    for (int j=0;j<9;j++) *(float4*)(wv + 4*j) = wp4[j];
    wp4 += 9;
    const float* pp = pb + g*60;
    #pragma unroll
    for (int c=0;c<4;c++){
      #pragma unroll
      for (int r=0;r<3;r++){
        const float* pp2 = pp + c*15 + r*5;
        float W0=wv[c*9+r*3], W1=wv[c*9+r*3+1], W2=wv[c*9+r*3+2];
        float p0=pp2[0], p1=pp2[1], p2=pp2[2], p3=pp2[3], p4=pp2[4];
        a0 += p0*W0 + p1*W1 + p2*W2;
        a1 += p1*W0 + p2*W1 + p3*W2;
        a2 += p2*W0 + p3*W1 + p4*W2;
      }
    }
  }
  if (half == 1){ red[o*3]=a0; red[o*3+1]=a1; red[o*3+2]=a2; }
  __syncthreads();
  if (half == 0){
    float* pp = part + (((size_t)q*256 + n)*128 + o)*3;
    pp[0] = a0 + red[o*3];
    pp[1] = a1 + red[o*3+1];
    pp[2] = a2 + red[o*3+2];
  }
}

// ---------------- cd tail: combine partials, pool, fc1, fc2 ----------------
__global__ __launch_bounds__(128) void cd_tail_kernel(
    const float* __restrict__ part,   // (8,256,128,3)
    const int*   __restrict__ clsb,
    const float* __restrict__ bcv,    // (80,128)
    const float* __restrict__ cstyle, // (2,80,32)
    const float* __restrict__ W1,     // (80,160,128)
    const float* __restrict__ b1,     // (80,128)
    const float* __restrict__ W2,     // (80,128,1)
    const float* __restrict__ b2,     // (80,1)
    float* __restrict__ pChar)        // (256)
{
  __shared__ float feat[160];
  __shared__ float red2[2];
  int n = blockIdx.x, tid = threadIdx.x;
  int b = n >> 7;
  int e = clsb[n];
  int o = tid;
  float a0=0.f, a1=0.f, a2=0.f;
  #pragma unroll
  for (int q=0;q<8;q++){
    const float* p = part + (((size_t)q*256 + n)*128 + o)*3;
    a0 += p[0]; a1 += p[1]; a2 += p[2];
  }
  float bb = bcv[e*128 + o];
  a0 += bb; a1 += bb; a2 += bb;
  feat[o] = (lrelu(a0)+lrelu(a1)+lrelu(a2)) * (1.f/3.f);
  if (tid < 32) feat[128+tid] = cstyle[(b*80 + e)*32 + tid];
  __syncthreads();

  float s = b1[e*128 + o];
  for (int d=0;d<160;d++) s += feat[d]*W1[(e*160 + d)*128 + o];
  float h = s > 0.f ? s : 0.f;
  float contrib = h * W2[e*128 + o];
  #pragma unroll
  for (int off=32; off>0; off>>=1) contrib += __shfl_down(contrib, off, 64);
  if ((tid & 63) == 0) red2[tid>>6] = contrib;
  __syncthreads();
  if (tid == 0) pChar[n] = red2[0] + red2[1] + b2[e];
}

// ---------------- chain runner ----------------
template<int SA2,int SA4,int SA5,int SA6,int SA7>
static void run_chain(const float* x, const float* label, const float* g_style,
                      const float* spaced, const float* cstyle,
                      const float* sp1, const float* sp2,
                      const float* in_w, const float* in_b,
                      const float* c1w1, const float* c1b1,
                      const float* c1w2, const float* c1b2,
                      const float* c2w,  const float* c2b,
                      const float* c3w1, const float* c3b1,
                      const float* c3w2, const float* c3b2,
                      const float* fm_w, const float* fm_b,
                      const float* cdw,  const float* cdb,
                      const float* fc1w, const float* fc1b,
                      const float* fc2w, const float* fc2b,
                      float* out, char* ws, size_t r1_off, size_t tail_off,
                      hipStream_t stream){
  float* R0 = (float*)ws;
  float* R1 = (float*)(ws + r1_off);
  float* tail = (float*)(ws + tail_off);
  float* map6 = tail;            // 32768
  float* map1 = tail + 32768;    // 384
  float* map2 = tail + 33152;    // 768
  float* s1   = tail + 33920;    // 64
  float* s2   = tail + 33984;    // 128
  int*   clsb = (int*)(tail + 34112);  // 256
  float* cdp  = R0 + 524288;     // cd partials: 786432 floats (3 MB) at +2 MB into R0

  style_kernel<<<1,256,0,stream>>>(g_style, sp1, sp2, s1, s2);
  cls_kernel<<<1,256,0,stream>>>(label, clsb);
  map3_kernel<32,96,64,64><<<1,128,0,stream>>>(s1, c1w1, c1b1, map1);
  map3_kernel<64,192,128,128><<<1,256,0,stream>>>(s2, c2w, c2b, map2);
  map6_kernel<<<128,256,0,stream>>>(spaced, label, c3w1, c3b1, map6);

  // h1 (2,64,58,512) -> R1
  conv_in_kernel<<<dim3(116,8,2),256,0,stream>>>(x, in_w, in_b, R1);
  // A2: main over 64ch -> R0 partials; combine w/ map1   (spatial 28672 / 1024 = 28)
  conv3_main4<64,96,58,512,64,8,SA2><<<dim3(28,8*SA2,2),256,0,stream>>>(R1, c1w1, R0);
  combine_kernel<SA2,1,64,56,512><<<3584,256,0,stream>>>(R0, map1, nullptr);
  // P3 (2,64,28,256) -> R1
  pool2_kernel<<<3584,256,0,stream>>>(R0, R1, 56, 512, 917504);
  // A4: main 64ch -> R0 partials; combine bias   (spatial 6656 -> 7 blocks)
  conv3_main4<64,64,28,256,128,8,SA4><<<dim3(7,16*SA4,2),256,0,stream>>>(R1, c1w2, R0);
  combine_kernel<SA4,0,128,26,256><<<1664,256,0,stream>>>(R0, nullptr, c1b2);
  // A5: main 128ch -> R1 partials; combine w/ map2   (spatial 6144 -> 6 blocks)
  conv3_main4<128,192,26,256,128,8,SA5><<<dim3(6,16*SA5,2),256,0,stream>>>(R0, c2w, R1);
  combine_kernel<SA5,1,128,24,256><<<1536,256,0,stream>>>(R1, map2, nullptr);
  // P5 (2,128,12,128) -> R0
  pool2_kernel<<<1536,256,0,stream>>>(R1, R0, 24, 256, 393216);
  // A6: main 128ch -> R1 partials; combine w/ map6
  conv3_main1<128,240,12,128,128,8,SA6><<<dim3(5,16*SA6,2),256,0,stream>>>(R0, c3w1, R1);
  combine_kernel<SA6,2,128,10,128><<<320,256,0,stream>>>(R1, map6, nullptr);
  // P6 (2,128,5,64) -> R0
  pool2_kernel<<<320,256,0,stream>>>(R1, R0, 10, 128, 81920);
  // A7: main 128ch -> R1 partials; combine bias
  conv3_main1<128,128,5,64,256,4,SA7><<<dim3(1,64*SA7,2),256,0,stream>>>(R0, c3w2, R1);
  combine_kernel<SA7,0,256,3,64><<<96,256,0,stream>>>(R1, nullptr, c3b2);
  // pM -> out[0..128)
  fm_kernel<<<128,256,0,stream>>>(R1, fm_w, fm_b, out);
  // pChar: split conv partials (8-way) then tail
  cd_conv_kernel<<<2048,256,0,stream>>>(R1, clsb, cdw, cdp);
  cd_tail_kernel<<<256,128,0,stream>>>(cdp, clsb, cdb, cstyle, fc1w, fc1b, fc2w, fc2b, out + 128);
}

extern "C" void kernel_launch(void* const* d_in, const int* in_sizes, int n_in,
                              void* d_out, int out_size, void* d_ws, size_t ws_size,
                              hipStream_t stream){
  (void)in_sizes; (void)n_in; (void)out_size;
  const float* x      = (const float*)d_in[0];
  const float* label  = (const float*)d_in[1];
  const float* g_style= (const float*)d_in[2];
  const float* spaced = (const float*)d_in[3];
  const float* cstyle = (const float*)d_in[4];
  const float* sp1    = (const float*)d_in[5];
  const float* sp2    = (const float*)d_in[6];
  const float* in_w   = (const float*)d_in[7];
  const float* in_b   = (const float*)d_in[8];
  const float* c1w1   = (const float*)d_in[9];
  const float* c1b1   = (const float*)d_in[10];
  const float* c1w2   = (const float*)d_in[11];
  const float* c1b2   = (const float*)d_in[12];
  const float* c2w    = (const float*)d_in[13];
  const float* c2b    = (const float*)d_in[14];
  const float* c3w1   = (const float*)d_in[15];
  const float* c3b1   = (const float*)d_in[16];
  const float* c3w2   = (const float*)d_in[17];
  const float* c3b2   = (const float*)d_in[18];
  const float* fm_w   = (const float*)d_in[19];
  const float* fm_b   = (const float*)d_in[20];
  const float* cdw    = (const float*)d_in[21];
  const float* cdb    = (const float*)d_in[22];
  const float* fc1w   = (const float*)d_in[23];
  const float* fc1b   = (const float*)d_in[24];
  const float* fc2w   = (const float*)d_in[25];
  const float* fc2b   = (const float*)d_in[26];
  float* out = (float*)d_out;
  char* ws = (char*)d_ws;

  if (ws_size >= 56000000ULL){
    run_chain<2,4,4,8,8>(x,label,g_style,spaced,cstyle,sp1,sp2,in_w,in_b,c1w1,c1b1,c1w2,c1b2,
                         c2w,c2b,c3w1,c3b1,c3w2,c3b2,fm_w,fm_b,cdw,cdb,fc1w,fc1b,fc2w,fc2b,
                         out, ws, 29507584ULL, 29360128ULL, stream);
  } else {
    run_chain<1,2,2,4,4>(x,label,g_style,spaced,cstyle,sp1,sp2,in_w,in_b,c1w1,c1b1,c1w2,c1b2,
                         c2w,c2b,c3w1,c3b1,c3w2,c3b2,fm_w,fm_b,cdw,cdb,fc1w,fc1b,fc2w,fc2b,
                         out, ws, 14827520ULL, 14680064ULL, stream);
  }
}

// Round 6
// 336.477 us; speedup vs baseline: 3.0169x; 1.1995x over previous
//
#include <hip/hip_runtime.h>
#include <hip/hip_bf16.h>

#define LEAKC 0.1f

__device__ __forceinline__ float lrelu(float v){ return v > 0.f ? v : LEAKC*v; }
__device__ __forceinline__ ushort f2b(float f){
  __hip_bfloat16 h = __float2bfloat16(f);
  return *reinterpret_cast<ushort*>(&h);
}

typedef __attribute__((ext_vector_type(8))) short bf16x8;
typedef __attribute__((ext_vector_type(4))) float f32x4;

// ---------------- styles ----------------
__global__ void style_kernel(const float* __restrict__ g,
                             const float* __restrict__ sp1,
                             const float* __restrict__ sp2,
                             float* __restrict__ s1, float* __restrict__ s2){
  int t = threadIdx.x;
  if (t < 64){
    int b = t >> 5, j = t & 31;
    float a = 0.f;
    for (int k=0;k<256;k++) a += g[b*256+k]*sp1[j*256+k];
    s1[t] = a;
  } else if (t < 192){
    int u = t - 64;
    int b = u >> 6, j = u & 63;
    float a = 0.f;
    for (int k=0;k<256;k++) a += g[b*256+k]*sp2[j*256+k];
    s2[u] = a;
  }
}

// ---------------- cls ----------------
__global__ void cls_kernel(const float* __restrict__ label, int* __restrict__ cls){
  int n = threadIdx.x;
  int b = n >> 7, t = n & 127;
  const float* p = label + (t*2 + b)*80;
  float best = p[0]; int bi = 0;
  for (int c=1;c<80;c++){ float v = p[c]; if (v > best){ best = v; bi = c; } }
  cls[n] = bi;
}

// ---------------- input conv 7x7 -> bf16 out ----------------
__global__ void conv_in_kernel(const float* __restrict__ x,
                               const float* __restrict__ wgt,
                               const float* __restrict__ bias,
                               ushort* __restrict__ out){
  int hw = blockIdx.x*256 + threadIdx.x;
  int y = hw >> 9, w = hw & 511;
  int b = blockIdx.z;
  int o0 = blockIdx.y * 8;
  float acc[8];
  #pragma unroll
  for (int i=0;i<8;i++) acc[i] = bias[o0+i];
  for (int kh=0;kh<7;kh++){
    const float* ip = x + (b*64 + y + kh)*512;
    #pragma unroll
    for (int kw=0;kw<7;kw++){
      int wi = w + kw - 3;
      float v = (wi>=0 && wi<512) ? ip[wi] : 0.f;
      #pragma unroll
      for (int i=0;i<8;i++) acc[i] += v * wgt[(o0+i)*49 + kh*7 + kw];
    }
  }
  #pragma unroll
  for (int i=0;i<8;i++)
    out[((b*64 + o0+i)*58 + y)*512 + w] = f2b(lrelu(acc[i]));
}

// ---------------- weight repack: wb[n][(kh*3+kw)*CM + c] = bf16(w[n][c][kh][kw]) ----------------
template<int CM,int CTOT,int COUT>
__global__ void repack_kernel(const float* __restrict__ w, ushort* __restrict__ wb){
  int i = blockIdx.x*256 + threadIdx.x;
  if (i >= COUT*9*CM) return;
  int c = i % CM; int r = i / CM; int t = r % 9; int n = r / 9;
  wb[i] = f2b(w[((size_t)n*CTOT + c)*9 + t]);
}

// ---------------- MFMA conv: 3x3, pad(0,1), BM=64 (one w-strip), BN=64, K=CM*9 ----------------
// MODE 0: +bias[n]; MODE 1: 3-value map (b,n,{left,mid,right}); OUTBF: write bf16 else f32
template<int CM,int WID,int HIN,int COUT,int MODE,int OUTBF>
__global__ __launch_bounds__(256) void conv_mfma(
    const ushort* __restrict__ in,   // bf16 (2,CM,HIN,WID)
    const ushort* __restrict__ Wb,   // bf16 (COUT, CM*9)
    const float*  __restrict__ mb,   // map (2,COUT,3) or bias (COUT)
    float* __restrict__ outf,
    ushort* __restrict__ outh){
  constexpr int HOUT = HIN - 2;
  constexpr int KTOT = CM*9;
  constexpr int SLABS = CM/32;
  constexpr int NST = 3*SLABS;
  __shared__ ushort A[2][66][40];
  int tid = threadIdx.x, lane = tid & 63, wave = tid >> 6;
  int mt = blockIdx.x;
  int y  = mt / (WID/64), w0 = (mt % (WID/64))*64;
  int n0 = blockIdx.y*64;
  int b  = blockIdx.z;

  f32x4 acc[4];
  #pragma unroll
  for (int nf=0;nf<4;nf++) acc[nf] = (f32x4){0.f,0.f,0.f,0.f};

  auto stage = [&](int s, int bufi){
    int kh = s / SLABS;
    int c0 = (s % SLABS)*32;
    const ushort* base = in + ((size_t)(b*CM + c0)*HIN + (y+kh))*WID;
    int c2 = (tid & 15)*2, m0v = (tid >> 4)*2*2;           // m0v in {0,4,...,60}
    const ushort* p0 = base + (size_t)c2*HIN*WID + w0 + m0v;
    const ushort* p1 = p0 + (size_t)HIN*WID;
    ushort4 va = *(const ushort4*)p0;
    ushort4 vb = *(const ushort4*)p1;
    uint* dst = (uint*)&A[bufi][1+m0v][c2];                // row stride = 20 uints
    dst[0]  = (uint)va.x | ((uint)vb.x << 16);
    dst[20] = (uint)va.y | ((uint)vb.y << 16);
    dst[40] = (uint)va.z | ((uint)vb.z << 16);
    dst[60] = (uint)va.w | ((uint)vb.w << 16);
    if (tid < 64){
      int c = tid & 31, side = tid >> 5;
      int w = side ? (w0 + 64) : (w0 - 1);
      ushort v = 0;
      if (w >= 0 && w < WID) v = base[(size_t)c*HIN*WID + w];
      A[bufi][side ? 65 : 0][c] = v;
    }
  };

  stage(0, 0);
  __syncthreads();
  for (int s = 0; s < NST; ++s){
    int cur = s & 1;
    if (s + 1 < NST) stage(s+1, cur ^ 1);
    int kh = s / SLABS;
    int c0 = (s % SLABS)*32;
    #pragma unroll
    for (int kw = 0; kw < 3; ++kw){
      bf16x8 a = *(bf16x8*)&A[cur][wave*16 + (lane & 15) + kw][(lane >> 4)*8];
      #pragma unroll
      for (int nf = 0; nf < 4; ++nf){
        const ushort* wp = Wb + (size_t)(n0 + nf*16 + (lane & 15))*KTOT
                              + (kh*3 + kw)*CM + c0 + (lane >> 4)*8;
        bf16x8 bb = *(const bf16x8*)wp;
        acc[nf] = __builtin_amdgcn_mfma_f32_16x16x32_bf16(a, bb, acc[nf], 0, 0, 0);
      }
    }
    __syncthreads();
  }

  int mrow = wave*16 + ((lane >> 4) << 2);
  int w = w0 + mrow;
  #pragma unroll
  for (int nf = 0; nf < 4; ++nf){
    int n = n0 + nf*16 + (lane & 15);
    float r0 = acc[nf][0], r1 = acc[nf][1], r2 = acc[nf][2], r3 = acc[nf][3];
    if (MODE == 0){
      float bb = mb[n];
      r0 += bb; r1 += bb; r2 += bb; r3 += bb;
    } else {
      const float* m3 = mb + (size_t)(b*COUT + n)*3;
      float mL = m3[0], mM = m3[1], mR = m3[2];
      r0 += (w == 0) ? mL : ((w   == WID-1) ? mR : mM);
      r1 += (w+1 == WID-1) ? mR : mM;
      r2 += (w+2 == WID-1) ? mR : mM;
      r3 += (w+3 == WID-1) ? mR : mM;
    }
    r0 = lrelu(r0); r1 = lrelu(r1); r2 = lrelu(r2); r3 = lrelu(r3);
    size_t off = ((size_t)(b*COUT + n)*HOUT + y)*WID + w;
    if (OUTBF){
      ushort4 o = make_ushort4(f2b(r0), f2b(r1), f2b(r2), f2b(r3));
      *(ushort4*)(outh + off) = o;
    } else {
      *(float4*)(outf + off) = make_float4(r0, r1, r2, r3);
    }
  }
}

// ---------------- f32 3x3 conv (small layers), K-split partials ----------------
template<int CM,int CTOT,int HIN,int WID,int COUT,int OPT,int SPLIT>
__global__ void conv3_main1(const float* __restrict__ in,
                            const float* __restrict__ wgt,
                            float* __restrict__ part){
  constexpr int HOUT = HIN - 2;
  constexpr int CSPLIT = CM / SPLIT;
  constexpr int N = 2*COUT*HOUT*WID;
  int hw0 = blockIdx.x*256 + threadIdx.x;
  if (hw0 >= HOUT*WID) return;
  int y = hw0 / WID, w0 = hw0 % WID;
  int b = blockIdx.z;
  int split = blockIdx.y % SPLIT;
  int o0 = (blockIdx.y / SPLIT) * OPT;

  float acc[OPT];
  #pragma unroll
  for (int i=0;i<OPT;i++) acc[i] = 0.f;

  const bool lok = (w0 > 0), rok = (w0 + 1) < WID;
  int c0 = split * CSPLIT;
  for (int c=c0; c<c0+CSPLIT; c++){
    const float* rp = in + ((size_t)(b*CM + c)*HIN + y)*WID + w0;
    #pragma unroll
    for (int kh=0;kh<3;kh++){
      float v0 = lok ? rp[kh*WID - 1] : 0.f;
      float v1 = rp[kh*WID];
      float v2 = rok ? rp[kh*WID + 1] : 0.f;
      #pragma unroll
      for (int i=0;i<OPT;i++){
        const float* wq = wgt + ((size_t)(o0+i)*CTOT + c)*9 + kh*3;
        acc[i] += v0*wq[0] + v1*wq[1] + v2*wq[2];
      }
    }
  }
  #pragma unroll
  for (int i=0;i<OPT;i++)
    part[(size_t)split*N + ((size_t)(b*COUT + o0+i)*HOUT + y)*WID + w0] = acc[i];
}

// ---------------- combine partials + map + lrelu ----------------
template<int SPLIT,int MODE,int COUT,int HOUT,int WID>
__global__ __launch_bounds__(256) void combine_kernel(float* __restrict__ part,
                                                      const float* __restrict__ mapv,
                                                      const float* __restrict__ bias){
  constexpr int N = 2*COUT*HOUT*WID;
  int idx = (blockIdx.x*256 + threadIdx.x)*4;
  if (idx >= N) return;
  float4 v = *(float4*)(part + idx);
  #pragma unroll
  for (int s=1;s<SPLIT;s++){
    float4 u = *(const float4*)(part + (size_t)s*N + idx);
    v.x += u.x; v.y += u.y; v.z += u.z; v.w += u.w;
  }
  int w = idx % WID;
  int r = idx / WID;
  int bo = r / HOUT;
  int o = bo % COUT, b = bo / COUT;
  float* av = (float*)&v;
  if (MODE == 0){
    float bb = bias[o];
    #pragma unroll
    for (int j=0;j<4;j++) av[j] += bb;
  } else if (MODE == 1){
    const float* m = mapv + (size_t)(b*COUT + o)*3;
    #pragma unroll
    for (int j=0;j<4;j++){
      int wj = w + j;
      av[j] += (wj == 0) ? m[0] : ((wj == WID-1) ? m[2] : m[1]);
    }
  } else {
    const float* m = mapv + ((size_t)(b*COUT + o))*WID + w;
    #pragma unroll
    for (int j=0;j<4;j++) av[j] += m[j];
  }
  #pragma unroll
  for (int j=0;j<4;j++) av[j] = lrelu(av[j]);
  *(float4*)(part + idx) = v;
}

// ---------------- 3-value style map ----------------
template<int CS,int CTOT,int COUT,int COFF>
__global__ void map3_kernel(const float* __restrict__ style,
                            const float* __restrict__ wgt,
                            const float* __restrict__ bias,
                            float* __restrict__ mapv){
  int t = threadIdx.x;
  if (t >= 2*COUT) return;
  int b = t / COUT, o = t % COUT;
  float S0=0.f, S1=0.f, S2=0.f;
  for (int c=0;c<CS;c++){
    float s = style[b*CS + c];
    const float* wq = wgt + ((size_t)o*CTOT + COFF + c)*9;
    S0 += s*(wq[0]+wq[3]+wq[6]);
    S1 += s*(wq[1]+wq[4]+wq[7]);
    S2 += s*(wq[2]+wq[5]+wq[8]);
  }
  float bb = bias[o];
  mapv[t*3+0] = S1+S2+bb;
  mapv[t*3+1] = S0+S1+S2+bb;
  mapv[t*3+2] = S0+S1+bb;
}

// ---------------- A6 column map ----------------
__global__ void map6_kernel(const float* __restrict__ spaced,
                            const float* __restrict__ label,
                            const float* __restrict__ wgt,
                            const float* __restrict__ bias,
                            float* __restrict__ mapv){
  int n = blockIdx.x*256 + threadIdx.x;
  int w = n & 127, o = (n >> 7) & 127, b = n >> 14;
  float a = bias[o];
  #pragma unroll
  for (int t=0;t<3;t++){
    int j = w + t - 1;
    if (j < 0 || j >= 128) continue;
    const float* sp = spaced + (j*2 + b)*32;
    const float* lb = label + (j*2 + b)*80;
    for (int c=0;c<32;c++){
      const float* wq = wgt + ((size_t)o*240 + 128 + c)*9 + t;
      a += sp[c]*(wq[0]+wq[3]+wq[6]);
    }
    for (int c=0;c<80;c++){
      const float* wq = wgt + ((size_t)o*240 + 160 + c)*9 + t;
      a += lb[c]*(wq[0]+wq[3]+wq[6]);
    }
  }
  mapv[n] = a;
}

// ---------------- 2x2 mean pool (f32 -> f32) ----------------
__global__ void pool2_kernel(const float* __restrict__ in, float* __restrict__ out,
                             int H, int W, int total){
  int n = blockIdx.x*256 + threadIdx.x;
  if (n >= total) return;
  int Wo = W >> 1;
  int wo = n % Wo;
  int r = n / Wo;
  int Ho = H >> 1;
  int ho = r % Ho;
  int bc = r / Ho;
  const float* p = in + (bc*H + 2*ho)*W + 2*wo;
  out[n] = 0.25f*(p[0] + p[1] + p[W] + p[W+1]);
}

// ---------------- 2x2 mean pool (f32 -> bf16) ----------------
__global__ void pool2_bf16_kernel(const float* __restrict__ in, ushort* __restrict__ out,
                                  int H, int W, int total){
  int n = blockIdx.x*256 + threadIdx.x;
  if (n >= total) return;
  int Wo = W >> 1;
  int wo = n % Wo;
  int r = n / Wo;
  int Ho = H >> 1;
  int ho = r % Ho;
  int bc = r / Ho;
  const float* p = in + (bc*H + 2*ho)*W + 2*wo;
  out[n] = f2b(0.25f*(p[0] + p[1] + p[W] + p[W+1]));
}

// ---------------- pM ----------------
__global__ __launch_bounds__(256) void fm_kernel(const float* __restrict__ A7,
                          const float* __restrict__ fw,
                          const float* __restrict__ fb,
                          float* __restrict__ out){
  __shared__ float red[4];
  int n = blockIdx.x;
  int b = n >> 6, w = n & 63;
  int c = threadIdx.x;
  float a = 0.f;
  #pragma unroll
  for (int r=0;r<3;r++){
    const float* ip = A7 + ((b*256+c)*3+r)*64;
    const float* wp = fw + (c*3+r)*3;
    #pragma unroll
    for (int kw=0;kw<3;kw++){
      int wi = w + kw - 1;
      if (wi>=0 && wi<64) a += ip[wi]*wp[kw];
    }
  }
  #pragma unroll
  for (int off=32; off>0; off>>=1) a += __shfl_down(a, off, 64);
  if ((threadIdx.x & 63) == 0) red[threadIdx.x>>6] = a;
  __syncthreads();
  if (threadIdx.x == 0) out[n] = red[0]+red[1]+red[2]+red[3] + fb[0];
}

// ---------------- cd conv partials: one block per (sample, channel-eighth) ----------------
__global__ __launch_bounds__(256) void cd_conv_kernel(
    const float* __restrict__ A7,
    const int*   __restrict__ clsb,
    const float* __restrict__ Wc,
    float* __restrict__ part)         // (8,256,128,3)
{
  __shared__ float patch[32*15];
  __shared__ float red[128*3];
  int blk = blockIdx.x;
  int n = blk >> 3, q = blk & 7;
  int b = n >> 7, t = n & 127;
  int e = clsb[n];
  int idx = t >> 1;
  int tid = threadIdx.x;
  int c0 = q * 32;

  for (int i=tid; i<32*15; i+=256){
    int c = i/15, rj = i%15, r = rj/5, j = rj%5;
    int wc = idx - 2 + j;
    patch[i] = (wc >= 0 && wc < 64) ? A7[((b*256+c0+c)*3+r)*64 + wc] : 0.f;
  }
  __syncthreads();

  int o = tid & 127, half = tid >> 7;
  int cbeg = half * 16;
  const float4* wp4 = (const float4*)(Wc + ((size_t)e*128 + o)*2304 + (size_t)(c0+cbeg)*9);
  const float* pb = patch + cbeg*15;
  float a0=0.f, a1=0.f, a2=0.f;
  for (int g=0; g<4; ++g){
    float wv[36];
    #pragma unroll
    for (int j=0;j<9;j++) *(float4*)(wv + 4*j) = wp4[j];
    wp4 += 9;
    const float* pp = pb + g*60;
    #pragma unroll
    for (int c=0;c<4;c++){
      #pragma unroll
      for (int r=0;r<3;r++){
        const float* pp2 = pp + c*15 + r*5;
        float W0=wv[c*9+r*3], W1=wv[c*9+r*3+1], W2=wv[c*9+r*3+2];
        float p0=pp2[0], p1=pp2[1], p2=pp2[2], p3=pp2[3], p4=pp2[4];
        a0 += p0*W0 + p1*W1 + p2*W2;
        a1 += p1*W0 + p2*W1 + p3*W2;
        a2 += p2*W0 + p3*W1 + p4*W2;
      }
    }
  }
  if (half == 1){ red[o*3]=a0; red[o*3+1]=a1; red[o*3+2]=a2; }
  __syncthreads();
  if (half == 0){
    float* pp = part + (((size_t)q*256 + n)*128 + o)*3;
    pp[0] = a0 + red[o*3];
    pp[1] = a1 + red[o*3+1];
    pp[2] = a2 + red[o*3+2];
  }
}

// ---------------- cd tail ----------------
__global__ __launch_bounds__(128) void cd_tail_kernel(
    const float* __restrict__ part,
    const int*   __restrict__ clsb,
    const float* __restrict__ bcv,
    const float* __restrict__ cstyle,
    const float* __restrict__ W1,
    const float* __restrict__ b1,
    const float* __restrict__ W2,
    const float* __restrict__ b2,
    float* __restrict__ pChar)
{
  __shared__ float feat[160];
  __shared__ float red2[2];
  int n = blockIdx.x, tid = threadIdx.x;
  int b = n >> 7;
  int e = clsb[n];
  int o = tid;
  float a0=0.f, a1=0.f, a2=0.f;
  #pragma unroll
  for (int q=0;q<8;q++){
    const float* p = part + (((size_t)q*256 + n)*128 + o)*3;
    a0 += p[0]; a1 += p[1]; a2 += p[2];
  }
  float bb = bcv[e*128 + o];
  a0 += bb; a1 += bb; a2 += bb;
  feat[o] = (lrelu(a0)+lrelu(a1)+lrelu(a2)) * (1.f/3.f);
  if (tid < 32) feat[128+tid] = cstyle[(b*80 + e)*32 + tid];
  __syncthreads();

  float s = b1[e*128 + o];
  for (int d=0;d<160;d++) s += feat[d]*W1[(e*160 + d)*128 + o];
  float h = s > 0.f ? s : 0.f;
  float contrib = h * W2[e*128 + o];
  #pragma unroll
  for (int off=32; off>0; off>>=1) contrib += __shfl_down(contrib, off, 64);
  if ((tid & 63) == 0) red2[tid>>6] = contrib;
  __syncthreads();
  if (tid == 0) pChar[n] = red2[0] + red2[1] + b2[e];
}

extern "C" void kernel_launch(void* const* d_in, const int* in_sizes, int n_in,
                              void* d_out, int out_size, void* d_ws, size_t ws_size,
                              hipStream_t stream){
  (void)in_sizes; (void)n_in; (void)out_size; (void)ws_size;
  const float* x      = (const float*)d_in[0];
  const float* label  = (const float*)d_in[1];
  const float* g_style= (const float*)d_in[2];
  const float* spaced = (const float*)d_in[3];
  const float* cstyle = (const float*)d_in[4];
  const float* sp1    = (const float*)d_in[5];
  const float* sp2    = (const float*)d_in[6];
  const float* in_w   = (const float*)d_in[7];
  const float* in_b   = (const float*)d_in[8];
  const float* c1w1   = (const float*)d_in[9];
  const float* c1b1   = (const float*)d_in[10];
  const float* c1w2   = (const float*)d_in[11];
  const float* c1b2   = (const float*)d_in[12];
  const float* c2w    = (const float*)d_in[13];
  const float* c2b    = (const float*)d_in[14];
  const float* c3w1   = (const float*)d_in[15];
  const float* c3b1   = (const float*)d_in[16];
  const float* c3w2   = (const float*)d_in[17];
  const float* c3b2   = (const float*)d_in[18];
  const float* fm_w   = (const float*)d_in[19];
  const float* fm_b   = (const float*)d_in[20];
  const float* cdw    = (const float*)d_in[21];
  const float* cdb    = (const float*)d_in[22];
  const float* fc1w   = (const float*)d_in[23];
  const float* fc1b   = (const float*)d_in[24];
  const float* fc2w   = (const float*)d_in[25];
  const float* fc2b   = (const float*)d_in[26];
  float* out = (float*)d_out;
  char* ws = (char*)d_ws;

  // layout (bytes); requires ws >= ~53.2 MB (round-5 run confirmed ws >= 56 MB)
  ushort* h1b = (ushort*)(ws + 0);                 // 7,602,176
  float*  A2  = (float*) (ws + 7602176);           // 14,680,064
  ushort* P3b = (ushort*)(ws + 22282240);          // 1,835,008
  ushort* A4b = (ushort*)(ws + 24117248);          // 3,407,872
  float*  A5  = (float*) (ws + 27525120);          // 6,291,456
  float*  P5  = (float*) (ws + 33816576);          // 1,572,864
  float*  A6p = (float*) (ws + 35389440);          // 10,485,760 (8 splits)
  float*  P6  = (float*) (ws + 45875200);          // 327,680
  float*  A7p = (float*) (ws + 46202880);          // 3,145,728 (8 splits)
  float*  cdp = (float*) (ws + 49348608);          // 3,145,728
  ushort* Wb2 = (ushort*)(ws + 52494336);          // 73,728
  ushort* Wb4 = (ushort*)(ws + 52568064);          // 147,456
  ushort* Wb5 = (ushort*)(ws + 52715520);          // 294,912
  float*  map6= (float*) (ws + 53010432);          // 131,072
  float*  map1= (float*) (ws + 53141504);          // 1,536
  float*  map2= (float*) (ws + 53143040);          // 3,072
  float*  s1  = (float*) (ws + 53146112);
  float*  s2  = (float*) (ws + 53146368);
  int*    clsb= (int*)   (ws + 53146880);

  style_kernel<<<1,256,0,stream>>>(g_style, sp1, sp2, s1, s2);
  cls_kernel<<<1,256,0,stream>>>(label, clsb);
  map3_kernel<32,96,64,64><<<1,128,0,stream>>>(s1, c1w1, c1b1, map1);
  map3_kernel<64,192,128,128><<<1,256,0,stream>>>(s2, c2w, c2b, map2);
  map6_kernel<<<128,256,0,stream>>>(spaced, label, c3w1, c3b1, map6);
  repack_kernel<64,96,64><<<144,256,0,stream>>>(c1w1, Wb2);
  repack_kernel<64,64,128><<<288,256,0,stream>>>(c1w2, Wb4);
  repack_kernel<128,192,128><<<576,256,0,stream>>>(c2w, Wb5);

  // h1 (bf16) -> h1b
  conv_in_kernel<<<dim3(116,8,2),256,0,stream>>>(x, in_w, in_b, h1b);
  // A2 = lrelu(conv(h1) + map1) : MFMA, f32 out
  conv_mfma<64,512,58,64,1,0><<<dim3(448,1,2),256,0,stream>>>(h1b, Wb2, map1, A2, nullptr);
  // P3 (bf16)
  pool2_bf16_kernel<<<3584,256,0,stream>>>(A2, P3b, 56, 512, 917504);
  // A4 = lrelu(conv(P3) + b) : MFMA, bf16 out
  conv_mfma<64,256,28,128,0,1><<<dim3(104,2,2),256,0,stream>>>(P3b, Wb4, c1b2, nullptr, A4b);
  // A5 = lrelu(conv(A4) + map2) : MFMA, f32 out
  conv_mfma<128,256,26,128,1,0><<<dim3(96,2,2),256,0,stream>>>(A4b, Wb5, map2, A5, nullptr);
  // P5
  pool2_kernel<<<1536,256,0,stream>>>(A5, P5, 24, 256, 393216);
  // A6 (f32 path)
  conv3_main1<128,240,12,128,128,8,8><<<dim3(5,16*8,2),256,0,stream>>>(P5, c3w1, A6p);
  combine_kernel<8,2,128,10,128><<<320,256,0,stream>>>(A6p, map6, nullptr);
  // P6
  pool2_kernel<<<320,256,0,stream>>>(A6p, P6, 10, 128, 81920);
  // A7 (f32 path)
  conv3_main1<128,128,5,64,256,4,8><<<dim3(1,64*8,2),256,0,stream>>>(P6, c3w2, A7p);
  combine_kernel<8,0,256,3,64><<<96,256,0,stream>>>(A7p, nullptr, c3b2);
  // pM
  fm_kernel<<<128,256,0,stream>>>(A7p, fm_w, fm_b, out);
  // pChar
  cd_conv_kernel<<<2048,256,0,stream>>>(A7p, clsb, cdw, cdp);
  cd_tail_kernel<<<256,128,0,stream>>>(cdp, clsb, cdb, cstyle, fc1w, fc1b, fc2w, fc2b, out + 128);
}